// Round 1
// baseline (428.403 us; speedup 1.0000x reference)
//
#include <hip/hip_runtime.h>
#include <hip/hip_bf16.h>

// Mamba block: B=4, L=512, D_MODEL=128, D_INNER=D_STATE=256
// pipeline: proj -> (delta,Bv,Cv) -> sequential scan -> out GEMM

#define MROWS 2048   // B*L
#define DM 128
#define DI 256
#define DS 256
#define LLEN 512
#define NB 4

// ---------------------------------------------------------------------------
// shared fp32 GEMM tile core: 64x64 tile, K-step 16, 256 threads, 4x4/thread
// A: row-major M x lda ; Bm: row-major K x ldb
// ---------------------------------------------------------------------------
__device__ __forceinline__ void gemm_tile_core(
    const float* __restrict__ A, int lda,
    const float* __restrict__ Bm, int ldb,
    int K, int r0, int n0,
    float (*__restrict__ As)[68], float (*__restrict__ Bs)[68],
    float acc[4][4])
{
    const int tid  = threadIdx.x;
    const int arow = tid >> 2;   // 0..63
    const int akq  = tid & 3;    // 0..3  (which float4 of the 16-wide k strip)
    const int bkr  = tid >> 4;   // 0..15
    const int bcq  = tid & 15;   // 0..15

    for (int k0 = 0; k0 < K; k0 += 16) {
        float4 av = *(const float4*)(A + (size_t)(r0 + arow) * lda + k0 + akq * 4);
        float4 bv = *(const float4*)(Bm + (size_t)(k0 + bkr) * ldb + n0 + bcq * 4);
        __syncthreads();   // previous iteration's reads complete
        As[akq * 4 + 0][arow] = av.x;
        As[akq * 4 + 1][arow] = av.y;
        As[akq * 4 + 2][arow] = av.z;
        As[akq * 4 + 3][arow] = av.w;
        *(float4*)&Bs[bkr][bcq * 4] = bv;
        __syncthreads();
        const int tx = tid & 15, ty = tid >> 4;
#pragma unroll
        for (int kk = 0; kk < 16; ++kk) {
            float4 a = *(const float4*)&As[kk][ty * 4];
            float4 b = *(const float4*)&Bs[kk][tx * 4];
            acc[0][0] += a.x * b.x; acc[0][1] += a.x * b.y; acc[0][2] += a.x * b.z; acc[0][3] += a.x * b.w;
            acc[1][0] += a.y * b.x; acc[1][1] += a.y * b.y; acc[1][2] += a.y * b.z; acc[1][3] += a.y * b.w;
            acc[2][0] += a.z * b.x; acc[2][1] += a.z * b.y; acc[2][2] += a.z * b.z; acc[2][3] += a.z * b.w;
            acc[3][0] += a.w * b.x; acc[3][1] += a.w * b.y; acc[3][2] += a.w * b.z; acc[3][3] += a.w * b.w;
        }
    }
}

// --------------------------- kernel 1: in_proj ------------------------------
// x (M x 128) @ W_in (128 x 512) -> xs (first 256 cols), sz = silu(z) (last 256)
__global__ __launch_bounds__(256) void k_proj(
    const float* __restrict__ x, const float* __restrict__ W_in,
    float* __restrict__ xs, float* __restrict__ sz)
{
    __shared__ float As[16][68];
    __shared__ float Bs[16][68];
    float acc[4][4] = {};
    const int r0 = blockIdx.y * 64;
    const int n0 = blockIdx.x * 64;
    gemm_tile_core(x, DM, W_in, 2 * DI, DM, r0, n0, As, Bs, acc);
    const int tx = threadIdx.x & 15, ty = threadIdx.x >> 4;
#pragma unroll
    for (int i = 0; i < 4; ++i) {
        const int r = r0 + ty * 4 + i;
#pragma unroll
        for (int j = 0; j < 4; ++j) {
            const int c = n0 + tx * 4 + j;
            float v = acc[i][j];
            if (c < DI) {
                xs[(size_t)r * DI + c] = v;
            } else {
                float s = v / (1.f + __expf(-v));   // silu
                sz[(size_t)r * DI + (c - DI)] = s;
            }
        }
    }
}

// ------------------- kernel 2: delta / u=Bv*xs / Cv -------------------------
// xs (M x 256) @ {W_delta, W_B, W_C} ; virtual N = 768
__global__ __launch_bounds__(256) void k_dbc(
    const float* __restrict__ xs,
    const float* __restrict__ Wd, const float* __restrict__ Wb, const float* __restrict__ Wc,
    float* __restrict__ dlt, float* __restrict__ u, float* __restrict__ cv)
{
    __shared__ float As[16][68];
    __shared__ float Bs[16][68];
    float acc[4][4] = {};
    const int bx = blockIdx.x;          // 0..11
    const int wsel = bx >> 2;           // 0: delta, 1: B, 2: C
    const int n0 = (bx & 3) * 64;
    const int r0 = blockIdx.y * 64;
    const float* Bm = (wsel == 0) ? Wd : ((wsel == 1) ? Wb : Wc);
    gemm_tile_core(xs, DI, Bm, DI, DI, r0, n0, As, Bs, acc);
    const int tx = threadIdx.x & 15, ty = threadIdx.x >> 4;
#pragma unroll
    for (int i = 0; i < 4; ++i) {
        const int r = r0 + ty * 4 + i;
#pragma unroll
        for (int j = 0; j < 4; ++j) {
            const int c = n0 + tx * 4 + j;
            float v = acc[i][j];
            size_t idx = (size_t)r * DI + c;
            if (wsel == 0)      dlt[idx] = v;
            else if (wsel == 1) u[idx]   = v * xs[idx];   // Bv * xs
            else                cv[idx]  = v;
        }
    }
}

// --------------------------- kernel 3: the scan -----------------------------
// one wave per (b, d): state[n=0..255] as 4 float4/lane; l-loop of 512 steps.
// state[n] = exp2(delta * A[d,n]*log2e) * state[n] + delta * u[b,l,n]
// y[b,l,d] = sum_n state[n]*Cv[b,l,n];   writes yp = y * silu(z)
__global__ __launch_bounds__(64) void k_scan(
    const float* __restrict__ dlt, const float* __restrict__ u,
    const float* __restrict__ cv, const float* __restrict__ A,
    const float* __restrict__ sz, float* __restrict__ yp)
{
    const int lane = threadIdx.x;
    const int bid  = blockIdx.x;
    const int b = bid >> 8;     // 0..3
    const int d = bid & 255;    // 0..255
    const float LOG2E = 1.44269504088896340736f;

    float4 a4 = *(const float4*)(A + (size_t)d * DS + lane * 4);
    a4.x *= LOG2E; a4.y *= LOG2E; a4.z *= LOG2E; a4.w *= LOG2E;

    const size_t base = (size_t)b * LLEN * DI;
    const float4* up = (const float4*)(u + base) + lane;    // +64 float4 per row
    const float4* cp = (const float4*)(cv + base) + lane;
    const float*  dp = dlt + base + d;                      // +256 per row
    const float*  sp = sz + base + d;
    float*        op = yp + base + d;

    float4 s = make_float4(0.f, 0.f, 0.f, 0.f);
    float4 uc = up[0];
    float4 cc = cp[0];
    float  dl = dp[0];

    for (int l = 0; l < LLEN; ++l) {
        const int lnext = (l + 1 < LLEN) ? (l + 1) : l;
        float4 un = up[(size_t)lnext * 64];
        float4 cn = cp[(size_t)lnext * 64];
        float  dn = dp[(size_t)lnext * 256];

        float p;
        float e0 = exp2f(dl * a4.x); s.x = e0 * s.x + dl * uc.x; p  = s.x * cc.x;
        float e1 = exp2f(dl * a4.y); s.y = e1 * s.y + dl * uc.y; p += s.y * cc.y;
        float e2 = exp2f(dl * a4.z); s.z = e2 * s.z + dl * uc.z; p += s.z * cc.z;
        float e3 = exp2f(dl * a4.w); s.w = e3 * s.w + dl * uc.w; p += s.w * cc.w;

#pragma unroll
        for (int off = 32; off > 0; off >>= 1)
            p += __shfl_xor(p, off);

        if (lane == 0)
            op[(size_t)l * DI] = p * sp[(size_t)l * DI];

        uc = un; cc = cn; dl = dn;
    }
}

// --------------------------- kernel 4: out GEMM -----------------------------
// yp (M x 256) @ W_out (256 x 128) -> out (M x 128)
__global__ __launch_bounds__(256) void k_out(
    const float* __restrict__ yp, const float* __restrict__ W_out,
    float* __restrict__ out)
{
    __shared__ float As[16][68];
    __shared__ float Bs[16][68];
    float acc[4][4] = {};
    const int r0 = blockIdx.y * 64;
    const int n0 = blockIdx.x * 64;
    gemm_tile_core(yp, DI, W_out, DM, DI, r0, n0, As, Bs, acc);
    const int tx = threadIdx.x & 15, ty = threadIdx.x >> 4;
#pragma unroll
    for (int i = 0; i < 4; ++i) {
        const int r = r0 + ty * 4 + i;
#pragma unroll
        for (int j = 0; j < 4; ++j) {
            const int c = n0 + tx * 4 + j;
            out[(size_t)r * DM + c] = acc[i][j];
        }
    }
}

// ---------------------------------------------------------------------------
extern "C" void kernel_launch(void* const* d_in, const int* in_sizes, int n_in,
                              void* d_out, int out_size, void* d_ws, size_t ws_size,
                              hipStream_t stream)
{
    const float* x       = (const float*)d_in[0];
    const float* W_in    = (const float*)d_in[1];
    const float* W_delta = (const float*)d_in[2];
    const float* W_B     = (const float*)d_in[3];
    const float* W_C     = (const float*)d_in[4];
    const float* W_out   = (const float*)d_in[5];
    const float* A       = (const float*)d_in[6];
    // d_in[7] = D, unused by the reference scan

    float* out = (float*)d_out;
    float* ws  = (float*)d_ws;

    const size_t S = (size_t)MROWS * DI;   // 2048*256 floats per plane
    float* xs  = ws;
    float* sz  = ws + S;
    float* dlt = ws + 2 * S;
    float* u   = ws + 3 * S;
    float* cv  = ws + 4 * S;
    float* yp  = ws + 5 * S;

    k_proj<<<dim3(8, 32), 256, 0, stream>>>(x, W_in, xs, sz);
    k_dbc <<<dim3(12, 32), 256, 0, stream>>>(xs, W_delta, W_B, W_C, dlt, u, cv);
    k_scan<<<dim3(1024), 64, 0, stream>>>(dlt, u, cv, A, sz, yp);
    k_out <<<dim3(2, 32), 256, 0, stream>>>(yp, W_out, out);
}

// Round 2
// 148.221 us; speedup vs baseline: 2.8903x; 2.8903x over previous
//
#include <hip/hip_runtime.h>
#include <hip/hip_bf16.h>

// Mamba block: B=4, L=512, D_MODEL=128, D_INNER=D_STATE=256
// pipeline: proj -> (delta,Bv,Cv) -> sequential scan -> out GEMM (fuses *silu(z))

#define MROWS 2048   // B*L
#define DM 128
#define DI 256
#define DS 256
#define LLEN 512

// ---------------------------------------------------------------------------
// shared fp32 GEMM tile core: 64x64 tile, K-step 16, 256 threads, 4x4/thread
// ---------------------------------------------------------------------------
__device__ __forceinline__ void gemm_tile_core(
    const float* __restrict__ A, int lda,
    const float* __restrict__ Bm, int ldb,
    int K, int r0, int n0,
    float (*__restrict__ As)[68], float (*__restrict__ Bs)[68],
    float acc[4][4])
{
    const int tid  = threadIdx.x;
    const int arow = tid >> 2;   // 0..63
    const int akq  = tid & 3;    // 0..3
    const int bkr  = tid >> 4;   // 0..15
    const int bcq  = tid & 15;   // 0..15

    for (int k0 = 0; k0 < K; k0 += 16) {
        float4 av = *(const float4*)(A + (size_t)(r0 + arow) * lda + k0 + akq * 4);
        float4 bv = *(const float4*)(Bm + (size_t)(k0 + bkr) * ldb + n0 + bcq * 4);
        __syncthreads();
        As[akq * 4 + 0][arow] = av.x;
        As[akq * 4 + 1][arow] = av.y;
        As[akq * 4 + 2][arow] = av.z;
        As[akq * 4 + 3][arow] = av.w;
        *(float4*)&Bs[bkr][bcq * 4] = bv;
        __syncthreads();
        const int tx = tid & 15, ty = tid >> 4;
#pragma unroll
        for (int kk = 0; kk < 16; ++kk) {
            float4 a = *(const float4*)&As[kk][ty * 4];
            float4 b = *(const float4*)&Bs[kk][tx * 4];
            acc[0][0] += a.x * b.x; acc[0][1] += a.x * b.y; acc[0][2] += a.x * b.z; acc[0][3] += a.x * b.w;
            acc[1][0] += a.y * b.x; acc[1][1] += a.y * b.y; acc[1][2] += a.y * b.z; acc[1][3] += a.y * b.w;
            acc[2][0] += a.z * b.x; acc[2][1] += a.z * b.y; acc[2][2] += a.z * b.z; acc[2][3] += a.z * b.w;
            acc[3][0] += a.w * b.x; acc[3][1] += a.w * b.y; acc[3][2] += a.w * b.z; acc[3][3] += a.w * b.w;
        }
    }
}

// --------------------------- kernel 1: in_proj ------------------------------
__global__ __launch_bounds__(256) void k_proj(
    const float* __restrict__ x, const float* __restrict__ W_in,
    float* __restrict__ xs, float* __restrict__ sz)
{
    __shared__ float As[16][68];
    __shared__ float Bs[16][68];
    float acc[4][4] = {};
    const int r0 = blockIdx.y * 64;
    const int n0 = blockIdx.x * 64;
    gemm_tile_core(x, DM, W_in, 2 * DI, DM, r0, n0, As, Bs, acc);
    const int tx = threadIdx.x & 15, ty = threadIdx.x >> 4;
#pragma unroll
    for (int i = 0; i < 4; ++i) {
        const int r = r0 + ty * 4 + i;
#pragma unroll
        for (int j = 0; j < 4; ++j) {
            const int c = n0 + tx * 4 + j;
            float v = acc[i][j];
            if (c < DI) {
                xs[(size_t)r * DI + c] = v;
            } else {
                float s = v / (1.f + __expf(-v));   // silu
                sz[(size_t)r * DI + (c - DI)] = s;
            }
        }
    }
}

// ------------------- kernel 2: delta / u=Bv*xs / Cv -------------------------
__global__ __launch_bounds__(256) void k_dbc(
    const float* __restrict__ xs,
    const float* __restrict__ Wd, const float* __restrict__ Wb, const float* __restrict__ Wc,
    float* __restrict__ dlt, float* __restrict__ u, float* __restrict__ cv)
{
    __shared__ float As[16][68];
    __shared__ float Bs[16][68];
    float acc[4][4] = {};
    const int bx = blockIdx.x;          // 0..11
    const int wsel = bx >> 2;           // 0: delta, 1: B, 2: C
    const int n0 = (bx & 3) * 64;
    const int r0 = blockIdx.y * 64;
    const float* Bm = (wsel == 0) ? Wd : ((wsel == 1) ? Wb : Wc);
    gemm_tile_core(xs, DI, Bm, DI, DI, r0, n0, As, Bs, acc);
    const int tx = threadIdx.x & 15, ty = threadIdx.x >> 4;
#pragma unroll
    for (int i = 0; i < 4; ++i) {
        const int r = r0 + ty * 4 + i;
#pragma unroll
        for (int j = 0; j < 4; ++j) {
            const int c = n0 + tx * 4 + j;
            float v = acc[i][j];
            size_t idx = (size_t)r * DI + c;
            if (wsel == 0)      dlt[idx] = v;
            else if (wsel == 1) u[idx]   = v * xs[idx];   // Bv * xs
            else                cv[idx]  = v;
        }
    }
}

// --------------------------- kernel 3: the scan -----------------------------
// one wave per (b, d). Group-of-8 software pipeline:
//   - register double-buffered prefetch of u/cv/delta rows (global latency
//     hidden under previous group's compute)
//   - per-lane partials p[0..7]; 8 independent butterflies pipeline the
//     shuffle latency instead of paying it per step
// b = blockIdx.x & 3 so each XCD (round-robin dispatch) sees one b's ~1.5MB
// working set -> L2-resident refetch.
#define SG 8
__global__ __launch_bounds__(64) void k_scan(
    const float* __restrict__ dlt, const float* __restrict__ u,
    const float* __restrict__ cv, const float* __restrict__ A,
    float* __restrict__ y)
{
    const int lane = threadIdx.x;
    const int bid  = blockIdx.x;
    const int b = bid & 3;
    const int d = bid >> 2;
    const float LOG2E = 1.44269504088896340736f;

    float4 a4 = *(const float4*)(A + (size_t)d * DS + lane * 4);
    a4.x *= LOG2E; a4.y *= LOG2E; a4.z *= LOG2E; a4.w *= LOG2E;

    const size_t base = (size_t)b * LLEN * DI;
    const float4* up = (const float4*)(u + base) + lane;    // +64 float4 per row
    const float4* cp = (const float4*)(cv + base) + lane;
    const float*  dp = dlt + base + d;                      // +256 per row
    float*        op = y + base + d;

    float4 s = make_float4(0.f, 0.f, 0.f, 0.f);

    float4 uA[SG], cA[SG], uB[SG], cB[SG];
    float  dA[SG], dB[SG];

    // prologue: load group 0 into A buffers
#pragma unroll
    for (int i = 0; i < SG; ++i) {
        uA[i] = up[(size_t)i * 64];
        cA[i] = cp[(size_t)i * 64];
        dA[i] = dp[(size_t)i * DI];
    }

#define COMPUTE_GROUP(UB, CB, DB, LG)                                          \
    {                                                                          \
        float p[SG];                                                           \
        _Pragma("unroll")                                                      \
        for (int i = 0; i < SG; ++i) {                                         \
            float dl = DB[i];                                                  \
            s.x = exp2f(dl * a4.x) * s.x + dl * UB[i].x;                       \
            s.y = exp2f(dl * a4.y) * s.y + dl * UB[i].y;                       \
            s.z = exp2f(dl * a4.z) * s.z + dl * UB[i].z;                       \
            s.w = exp2f(dl * a4.w) * s.w + dl * UB[i].w;                       \
            p[i] = s.x * CB[i].x + s.y * CB[i].y + s.z * CB[i].z + s.w * CB[i].w; \
        }                                                                      \
        _Pragma("unroll")                                                      \
        for (int i = 0; i < SG; ++i) {                                         \
            _Pragma("unroll")                                                  \
            for (int off = 32; off > 0; off >>= 1)                             \
                p[i] += __shfl_xor(p[i], off);                                 \
        }                                                                      \
        if (lane == 0) {                                                       \
            _Pragma("unroll")                                                  \
            for (int i = 0; i < SG; ++i)                                       \
                op[(size_t)((LG) + i) * DI] = p[i];                            \
        }                                                                      \
    }

#define PREFETCH_GROUP(UB, CB, DB, LG)                                         \
    {                                                                          \
        _Pragma("unroll")                                                      \
        for (int i = 0; i < SG; ++i) {                                         \
            UB[i] = up[(size_t)((LG) + i) * 64];                               \
            CB[i] = cp[(size_t)((LG) + i) * 64];                               \
            DB[i] = dp[(size_t)((LG) + i) * DI];                               \
        }                                                                      \
    }

    const int NG = LLEN / SG;   // 64 groups
    for (int g = 0; g < NG; g += 2) {
        // phase A: prefetch group g+1 into B, compute group g from A
        PREFETCH_GROUP(uB, cB, dB, (g + 1) * SG);
        COMPUTE_GROUP(uA, cA, dA, g * SG);
        // phase B: prefetch group g+2 into A, compute group g+1 from B
        if (g + 2 < NG) {
            PREFETCH_GROUP(uA, cA, dA, (g + 2) * SG);
        }
        COMPUTE_GROUP(uB, cB, dB, (g + 1) * SG);
    }
#undef COMPUTE_GROUP
#undef PREFETCH_GROUP
}

// --------------------------- kernel 4: out GEMM -----------------------------
// (y * silu(z)) (M x 256) @ W_out (256 x 128) -> out (M x 128)
// silu(z) multiply fused into the A-tile load.
__global__ __launch_bounds__(256) void k_out(
    const float* __restrict__ y, const float* __restrict__ sz,
    const float* __restrict__ W_out, float* __restrict__ out)
{
    __shared__ float As[16][68];
    __shared__ float Bs[16][68];
    float acc[4][4] = {};
    const int r0 = blockIdx.y * 64;
    const int n0 = blockIdx.x * 64;
    const int tid  = threadIdx.x;
    const int arow = tid >> 2;
    const int akq  = tid & 3;
    const int bkr  = tid >> 4;
    const int bcq  = tid & 15;

    for (int k0 = 0; k0 < DI; k0 += 16) {
        size_t aoff = (size_t)(r0 + arow) * DI + k0 + akq * 4;
        float4 av  = *(const float4*)(y + aoff);
        float4 szv = *(const float4*)(sz + aoff);
        av.x *= szv.x; av.y *= szv.y; av.z *= szv.z; av.w *= szv.w;
        float4 bv = *(const float4*)(W_out + (size_t)(k0 + bkr) * DM + n0 + bcq * 4);
        __syncthreads();
        As[akq * 4 + 0][arow] = av.x;
        As[akq * 4 + 1][arow] = av.y;
        As[akq * 4 + 2][arow] = av.z;
        As[akq * 4 + 3][arow] = av.w;
        *(float4*)&Bs[bkr][bcq * 4] = bv;
        __syncthreads();
        const int tx = tid & 15, ty = tid >> 4;
#pragma unroll
        for (int kk = 0; kk < 16; ++kk) {
            float4 a = *(const float4*)&As[kk][ty * 4];
            float4 b = *(const float4*)&Bs[kk][tx * 4];
            acc[0][0] += a.x * b.x; acc[0][1] += a.x * b.y; acc[0][2] += a.x * b.z; acc[0][3] += a.x * b.w;
            acc[1][0] += a.y * b.x; acc[1][1] += a.y * b.y; acc[1][2] += a.y * b.z; acc[1][3] += a.y * b.w;
            acc[2][0] += a.z * b.x; acc[2][1] += a.z * b.y; acc[2][2] += a.z * b.z; acc[2][3] += a.z * b.w;
            acc[3][0] += a.w * b.x; acc[3][1] += a.w * b.y; acc[3][2] += a.w * b.z; acc[3][3] += a.w * b.w;
        }
    }
    const int tx = tid & 15, ty = tid >> 4;
#pragma unroll
    for (int i = 0; i < 4; ++i) {
        const int r = r0 + ty * 4 + i;
#pragma unroll
        for (int j = 0; j < 4; ++j) {
            const int c = n0 + tx * 4 + j;
            out[(size_t)r * DM + c] = acc[i][j];
        }
    }
}

// ---------------------------------------------------------------------------
extern "C" void kernel_launch(void* const* d_in, const int* in_sizes, int n_in,
                              void* d_out, int out_size, void* d_ws, size_t ws_size,
                              hipStream_t stream)
{
    const float* x       = (const float*)d_in[0];
    const float* W_in    = (const float*)d_in[1];
    const float* W_delta = (const float*)d_in[2];
    const float* W_B     = (const float*)d_in[3];
    const float* W_C     = (const float*)d_in[4];
    const float* W_out   = (const float*)d_in[5];
    const float* A       = (const float*)d_in[6];
    // d_in[7] = D, unused by the reference scan

    float* out = (float*)d_out;
    float* ws  = (float*)d_ws;

    const size_t S = (size_t)MROWS * DI;   // 2048*256 floats per plane
    float* xs  = ws;
    float* sz  = ws + S;
    float* dlt = ws + 2 * S;
    float* u   = ws + 3 * S;
    float* cv  = ws + 4 * S;
    float* yv  = ws + 5 * S;

    k_proj<<<dim3(8, 32), 256, 0, stream>>>(x, W_in, xs, sz);
    k_dbc <<<dim3(12, 32), 256, 0, stream>>>(xs, W_delta, W_B, W_C, dlt, u, cv);
    k_scan<<<dim3(1024), 64, 0, stream>>>(dlt, u, cv, A, yv);
    k_out <<<dim3(2, 32), 256, 0, stream>>>(yv, sz, W_out, out);
}

// Round 3
// 138.582 us; speedup vs baseline: 3.0913x; 1.0696x over previous
//
#include <hip/hip_runtime.h>
#include <hip/hip_bf16.h>

// Mamba block: B=4, L=512, D_MODEL=128, D_INNER=D_STATE=256
// proj -> (delta,Bv,Cv) -> chunked 3-pass scan -> out GEMM (fuses *silu(z))

#define MROWS 2048   // B*L
#define DM 128
#define DI 256
#define DS 256
#define LLEN 512
#define LC 64        // chunk length == wave size
#define NC 8         // chunks

#define LOG2E 1.44269504088896340736f

// ---------------------------------------------------------------------------
// shared fp32 GEMM tile core: 64x64 tile, K-step 16, 256 threads, 4x4/thread
// ---------------------------------------------------------------------------
__device__ __forceinline__ void gemm_tile_core(
    const float* __restrict__ A, int lda,
    const float* __restrict__ Bm, int ldb,
    int K, int r0, int n0,
    float (*__restrict__ As)[68], float (*__restrict__ Bs)[68],
    float acc[4][4])
{
    const int tid  = threadIdx.x;
    const int arow = tid >> 2;   // 0..63
    const int akq  = tid & 3;    // 0..3
    const int bkr  = tid >> 4;   // 0..15
    const int bcq  = tid & 15;   // 0..15

    for (int k0 = 0; k0 < K; k0 += 16) {
        float4 av = *(const float4*)(A + (size_t)(r0 + arow) * lda + k0 + akq * 4);
        float4 bv = *(const float4*)(Bm + (size_t)(k0 + bkr) * ldb + n0 + bcq * 4);
        __syncthreads();
        As[akq * 4 + 0][arow] = av.x;
        As[akq * 4 + 1][arow] = av.y;
        As[akq * 4 + 2][arow] = av.z;
        As[akq * 4 + 3][arow] = av.w;
        *(float4*)&Bs[bkr][bcq * 4] = bv;
        __syncthreads();
        const int tx = tid & 15, ty = tid >> 4;
#pragma unroll
        for (int kk = 0; kk < 16; ++kk) {
            float4 a = *(const float4*)&As[kk][ty * 4];
            float4 b = *(const float4*)&Bs[kk][tx * 4];
            acc[0][0] += a.x * b.x; acc[0][1] += a.x * b.y; acc[0][2] += a.x * b.z; acc[0][3] += a.x * b.w;
            acc[1][0] += a.y * b.x; acc[1][1] += a.y * b.y; acc[1][2] += a.y * b.z; acc[1][3] += a.y * b.w;
            acc[2][0] += a.z * b.x; acc[2][1] += a.z * b.y; acc[2][2] += a.z * b.z; acc[2][3] += a.z * b.w;
            acc[3][0] += a.w * b.x; acc[3][1] += a.w * b.y; acc[3][2] += a.w * b.z; acc[3][3] += a.w * b.w;
        }
    }
}

// --------------------------- kernel 1: in_proj ------------------------------
__global__ __launch_bounds__(256) void k_proj(
    const float* __restrict__ x, const float* __restrict__ W_in,
    float* __restrict__ xs, float* __restrict__ sz)
{
    __shared__ float As[16][68];
    __shared__ float Bs[16][68];
    float acc[4][4] = {};
    const int r0 = blockIdx.y * 64;
    const int n0 = blockIdx.x * 64;
    gemm_tile_core(x, DM, W_in, 2 * DI, DM, r0, n0, As, Bs, acc);
    const int tx = threadIdx.x & 15, ty = threadIdx.x >> 4;
#pragma unroll
    for (int i = 0; i < 4; ++i) {
        const int r = r0 + ty * 4 + i;
#pragma unroll
        for (int j = 0; j < 4; ++j) {
            const int c = n0 + tx * 4 + j;
            float v = acc[i][j];
            if (c < DI) {
                xs[(size_t)r * DI + c] = v;
            } else {
                float s = v / (1.f + __expf(-v));   // silu
                sz[(size_t)r * DI + (c - DI)] = s;
            }
        }
    }
}

// ------------------- kernel 2: delta / u=Bv*xs / Cv -------------------------
__global__ __launch_bounds__(256) void k_dbc(
    const float* __restrict__ xs,
    const float* __restrict__ Wd, const float* __restrict__ Wb, const float* __restrict__ Wc,
    float* __restrict__ dlt, float* __restrict__ u, float* __restrict__ cv)
{
    __shared__ float As[16][68];
    __shared__ float Bs[16][68];
    float acc[4][4] = {};
    const int bx = blockIdx.x;          // 0..11
    const int wsel = bx >> 2;           // 0: delta, 1: B, 2: C
    const int n0 = (bx & 3) * 64;
    const int r0 = blockIdx.y * 64;
    const float* Bm = (wsel == 0) ? Wd : ((wsel == 1) ? Wb : Wc);
    gemm_tile_core(xs, DI, Bm, DI, DI, r0, n0, As, Bs, acc);
    const int tx = threadIdx.x & 15, ty = threadIdx.x >> 4;
#pragma unroll
    for (int i = 0; i < 4; ++i) {
        const int r = r0 + ty * 4 + i;
#pragma unroll
        for (int j = 0; j < 4; ++j) {
            const int c = n0 + tx * 4 + j;
            float v = acc[i][j];
            size_t idx = (size_t)r * DI + c;
            if (wsel == 0)      dlt[idx] = v;
            else if (wsel == 1) u[idx]   = v * xs[idx];   // Bv * xs
            else                cv[idx]  = v;
        }
    }
}

// ------------------------ chunked scan: unit mapping ------------------------
// 8192 units = (b:4, d:256, c:8). 4 waves/block share (b, chunk), consecutive
// d -> L1 reuse of u/cv rows. b = blk&3 keeps one batch per XCD (round-robin).
__device__ __forceinline__ void unit_map(int blk, int w, int& b, int& d, int& c)
{
    b = blk & 3;
    c = (blk >> 2) & 7;
    d = (blk >> 5) * 4 + w;
}

// --------------------- scan pass 1: chunk-local states ----------------------
// per (b,d,c): T_c = local scan from 0 over 64 steps; Dsum_c = sum delta.
__global__ __launch_bounds__(256) void k_scan1(
    const float* __restrict__ dlt, const float* __restrict__ u,
    const float* __restrict__ A,
    float* __restrict__ tc, float* __restrict__ dsum)
{
    const int lane = threadIdx.x & 63;
    const int w    = threadIdx.x >> 6;
    int b, d, c;
    unit_map(blockIdx.x, w, b, d, c);

    float4 a4 = *(const float4*)(A + (size_t)d * DS + lane * 4);
    a4.x *= LOG2E; a4.y *= LOG2E; a4.z *= LOG2E; a4.w *= LOG2E;

    const size_t base = (size_t)b * LLEN * DI + (size_t)c * LC * DI;
    const float4* up = (const float4*)(u + base) + lane;
    const float*  dp = dlt + base + d;

    // delta row for the whole chunk, one element per lane
    float dlv = dp[(size_t)lane * DI];

    float4 s = make_float4(0.f, 0.f, 0.f, 0.f);
    for (int l = 0; l < LC; ++l) {
        float  dl = __shfl(dlv, l);
        float4 uv = up[(size_t)l * 64];
        s.x = exp2f(dl * a4.x) * s.x + dl * uv.x;
        s.y = exp2f(dl * a4.y) * s.y + dl * uv.y;
        s.z = exp2f(dl * a4.z) * s.z + dl * uv.z;
        s.w = exp2f(dl * a4.w) * s.w + dl * uv.w;
    }

    float ds_ = dlv;
#pragma unroll
    for (int off = 32; off > 0; off >>= 1)
        ds_ += __shfl_xor(ds_, off);

    const size_t rb = ((size_t)(b * 256 + d)) * NC + c;
    *(float4*)(tc + rb * 256 + lane * 4) = s;
    if (lane == 0) dsum[rb] = ds_;
}

// ------------------- scan pass 2: combine chunk boundaries ------------------
// sequential over 8 chunks; writes s_init[c] in place over tc.
__global__ __launch_bounds__(256) void k_scan2(
    const float* __restrict__ A, float* __restrict__ tc,
    const float* __restrict__ dsum)
{
    const int lane = threadIdx.x & 63;
    const int w    = threadIdx.x >> 6;
    const int blk  = blockIdx.x;
    const int b = blk & 3;
    const int d = (blk >> 2) * 4 + w;

    float4 a4 = *(const float4*)(A + (size_t)d * DS + lane * 4);
    a4.x *= LOG2E; a4.y *= LOG2E; a4.z *= LOG2E; a4.w *= LOG2E;

    const size_t rb = ((size_t)(b * 256 + d)) * NC;
    float4 s = make_float4(0.f, 0.f, 0.f, 0.f);
#pragma unroll
    for (int c = 0; c < NC; ++c) {
        float* p = tc + (rb + c) * 256 + lane * 4;
        float4 T = *(const float4*)p;
        float  Dc = dsum[rb + c];
        *(float4*)p = s;                      // s_init[c]
        s.x = exp2f(a4.x * Dc) * s.x + T.x;
        s.y = exp2f(a4.y * Dc) * s.y + T.y;
        s.z = exp2f(a4.z * Dc) * s.z + T.z;
        s.w = exp2f(a4.w * Dc) * s.w + T.w;
    }
}

// ------------------- scan pass 3: outputs from s_init -----------------------
__global__ __launch_bounds__(256) void k_scan3(
    const float* __restrict__ dlt, const float* __restrict__ u,
    const float* __restrict__ cv, const float* __restrict__ A,
    const float* __restrict__ tc, float* __restrict__ y)
{
    const int lane = threadIdx.x & 63;
    const int w    = threadIdx.x >> 6;
    int b, d, c;
    unit_map(blockIdx.x, w, b, d, c);

    float4 a4 = *(const float4*)(A + (size_t)d * DS + lane * 4);
    a4.x *= LOG2E; a4.y *= LOG2E; a4.z *= LOG2E; a4.w *= LOG2E;

    const size_t base = (size_t)b * LLEN * DI + (size_t)c * LC * DI;
    const float4* up = (const float4*)(u + base) + lane;
    const float4* cp = (const float4*)(cv + base) + lane;
    const float*  dp = dlt + base + d;
    float*        op = y + base + d;

    float dlv = dp[(size_t)lane * DI];

    const size_t rb = ((size_t)(b * 256 + d)) * NC + c;
    float4 s = *(const float4*)(tc + rb * 256 + lane * 4);

    for (int l = 0; l < LC; ++l) {
        float  dl = __shfl(dlv, l);
        float4 uv = up[(size_t)l * 64];
        float4 cV = cp[(size_t)l * 64];
        s.x = exp2f(dl * a4.x) * s.x + dl * uv.x;
        s.y = exp2f(dl * a4.y) * s.y + dl * uv.y;
        s.z = exp2f(dl * a4.z) * s.z + dl * uv.z;
        s.w = exp2f(dl * a4.w) * s.w + dl * uv.w;
        float p = s.x * cV.x + s.y * cV.y + s.z * cV.z + s.w * cV.w;
#pragma unroll
        for (int off = 32; off > 0; off >>= 1)
            p += __shfl_xor(p, off);
        if (lane == 0)
            op[(size_t)l * DI] = p;
    }
}

// --------------------------- kernel 4: out GEMM -----------------------------
// (y * silu(z)) (M x 256) @ W_out (256 x 128) -> out (M x 128)
__global__ __launch_bounds__(256) void k_out(
    const float* __restrict__ y, const float* __restrict__ sz,
    const float* __restrict__ W_out, float* __restrict__ out)
{
    __shared__ float As[16][68];
    __shared__ float Bs[16][68];
    float acc[4][4] = {};
    const int r0 = blockIdx.y * 64;
    const int n0 = blockIdx.x * 64;
    const int tid  = threadIdx.x;
    const int arow = tid >> 2;
    const int akq  = tid & 3;
    const int bkr  = tid >> 4;
    const int bcq  = tid & 15;

    for (int k0 = 0; k0 < DI; k0 += 16) {
        size_t aoff = (size_t)(r0 + arow) * DI + k0 + akq * 4;
        float4 av  = *(const float4*)(y + aoff);
        float4 szv = *(const float4*)(sz + aoff);
        av.x *= szv.x; av.y *= szv.y; av.z *= szv.z; av.w *= szv.w;
        float4 bv = *(const float4*)(W_out + (size_t)(k0 + bkr) * DM + n0 + bcq * 4);
        __syncthreads();
        As[akq * 4 + 0][arow] = av.x;
        As[akq * 4 + 1][arow] = av.y;
        As[akq * 4 + 2][arow] = av.z;
        As[akq * 4 + 3][arow] = av.w;
        *(float4*)&Bs[bkr][bcq * 4] = bv;
        __syncthreads();
        const int tx = tid & 15, ty = tid >> 4;
#pragma unroll
        for (int kk = 0; kk < 16; ++kk) {
            float4 a = *(const float4*)&As[kk][ty * 4];
            float4 b = *(const float4*)&Bs[kk][tx * 4];
            acc[0][0] += a.x * b.x; acc[0][1] += a.x * b.y; acc[0][2] += a.x * b.z; acc[0][3] += a.x * b.w;
            acc[1][0] += a.y * b.x; acc[1][1] += a.y * b.y; acc[1][2] += a.y * b.z; acc[1][3] += a.y * b.w;
            acc[2][0] += a.z * b.x; acc[2][1] += a.z * b.y; acc[2][2] += a.z * b.z; acc[2][3] += a.z * b.w;
            acc[3][0] += a.w * b.x; acc[3][1] += a.w * b.y; acc[3][2] += a.w * b.z; acc[3][3] += a.w * b.w;
        }
    }
    const int tx = tid & 15, ty = tid >> 4;
#pragma unroll
    for (int i = 0; i < 4; ++i) {
        const int r = r0 + ty * 4 + i;
#pragma unroll
        for (int j = 0; j < 4; ++j) {
            const int c = n0 + tx * 4 + j;
            out[(size_t)r * DM + c] = acc[i][j];
        }
    }
}

// ---------------------------------------------------------------------------
extern "C" void kernel_launch(void* const* d_in, const int* in_sizes, int n_in,
                              void* d_out, int out_size, void* d_ws, size_t ws_size,
                              hipStream_t stream)
{
    const float* x       = (const float*)d_in[0];
    const float* W_in    = (const float*)d_in[1];
    const float* W_delta = (const float*)d_in[2];
    const float* W_B     = (const float*)d_in[3];
    const float* W_C     = (const float*)d_in[4];
    const float* W_out   = (const float*)d_in[5];
    const float* A       = (const float*)d_in[6];
    // d_in[7] = D, unused by the reference scan

    float* out = (float*)d_out;
    float* ws  = (float*)d_ws;

    const size_t S = (size_t)MROWS * DI;   // 2048*256 floats per plane (2 MB)
    float* xs  = ws;
    float* sz  = ws + S;
    float* dlt = ws + 2 * S;
    float* u   = ws + 3 * S;
    float* cv  = ws + 4 * S;
    float* yv  = ws + 5 * S;
    float* tc  = ws + 6 * S;               // 1024*8*256 floats = 8 MB
    float* dsm = ws + 6 * S + (size_t)1024 * NC * 256;  // 32 KB

    k_proj <<<dim3(8, 32), 256, 0, stream>>>(x, W_in, xs, sz);
    k_dbc  <<<dim3(12, 32), 256, 0, stream>>>(xs, W_delta, W_B, W_C, dlt, u, cv);
    k_scan1<<<dim3(2048), 256, 0, stream>>>(dlt, u, A, tc, dsm);
    k_scan2<<<dim3(256),  256, 0, stream>>>(A, tc, dsm);
    k_scan3<<<dim3(2048), 256, 0, stream>>>(dlt, u, cv, A, tc, yv);
    k_out  <<<dim3(2, 32), 256, 0, stream>>>(yv, sz, W_out, out);
}

// Round 4
// 120.348 us; speedup vs baseline: 3.5597x; 1.1515x over previous
//
#include <hip/hip_runtime.h>
#include <hip/hip_bf16.h>

// Mamba block: B=4, L=512, D_MODEL=128, D_INNER=D_STATE=256
// proj -> (delta,Bv,Cv) -> single-pass split-state scan -> out GEMM (fuses *silu(z))

#define MROWS 2048   // B*L
#define DM 128
#define DI 256
#define DS 256
#define LLEN 512
#define SGRP 16      // scan steps per software-pipeline group

// ---------------------------------------------------------------------------
// shared fp32 GEMM tile core: 64x64 tile, K-step 16, 256 threads, 4x4/thread
// ---------------------------------------------------------------------------
__device__ __forceinline__ void gemm_tile_core(
    const float* __restrict__ A, int lda,
    const float* __restrict__ Bm, int ldb,
    int K, int r0, int n0,
    float (*__restrict__ As)[68], float (*__restrict__ Bs)[68],
    float acc[4][4])
{
    const int tid  = threadIdx.x;
    const int arow = tid >> 2;   // 0..63
    const int akq  = tid & 3;    // 0..3
    const int bkr  = tid >> 4;   // 0..15
    const int bcq  = tid & 15;   // 0..15

    for (int k0 = 0; k0 < K; k0 += 16) {
        float4 av = *(const float4*)(A + (size_t)(r0 + arow) * lda + k0 + akq * 4);
        float4 bv = *(const float4*)(Bm + (size_t)(k0 + bkr) * ldb + n0 + bcq * 4);
        __syncthreads();
        As[akq * 4 + 0][arow] = av.x;
        As[akq * 4 + 1][arow] = av.y;
        As[akq * 4 + 2][arow] = av.z;
        As[akq * 4 + 3][arow] = av.w;
        *(float4*)&Bs[bkr][bcq * 4] = bv;
        __syncthreads();
        const int tx = tid & 15, ty = tid >> 4;
#pragma unroll
        for (int kk = 0; kk < 16; ++kk) {
            float4 a = *(const float4*)&As[kk][ty * 4];
            float4 b = *(const float4*)&Bs[kk][tx * 4];
            acc[0][0] += a.x * b.x; acc[0][1] += a.x * b.y; acc[0][2] += a.x * b.z; acc[0][3] += a.x * b.w;
            acc[1][0] += a.y * b.x; acc[1][1] += a.y * b.y; acc[1][2] += a.y * b.z; acc[1][3] += a.y * b.w;
            acc[2][0] += a.z * b.x; acc[2][1] += a.z * b.y; acc[2][2] += a.z * b.z; acc[2][3] += a.z * b.w;
            acc[3][0] += a.w * b.x; acc[3][1] += a.w * b.y; acc[3][2] += a.w * b.z; acc[3][3] += a.w * b.w;
        }
    }
}

// --------------------------- kernel 1: in_proj ------------------------------
__global__ __launch_bounds__(256) void k_proj(
    const float* __restrict__ x, const float* __restrict__ W_in,
    float* __restrict__ xs, float* __restrict__ sz)
{
    __shared__ float As[16][68];
    __shared__ float Bs[16][68];
    float acc[4][4] = {};
    const int r0 = blockIdx.y * 64;
    const int n0 = blockIdx.x * 64;
    gemm_tile_core(x, DM, W_in, 2 * DI, DM, r0, n0, As, Bs, acc);
    const int tx = threadIdx.x & 15, ty = threadIdx.x >> 4;
#pragma unroll
    for (int i = 0; i < 4; ++i) {
        const int r = r0 + ty * 4 + i;
#pragma unroll
        for (int j = 0; j < 4; ++j) {
            const int c = n0 + tx * 4 + j;
            float v = acc[i][j];
            if (c < DI) {
                xs[(size_t)r * DI + c] = v;
            } else {
                float s = v / (1.f + __expf(-v));   // silu
                sz[(size_t)r * DI + (c - DI)] = s;
            }
        }
    }
}

// ------------------- kernel 2: delta / u=Bv*xs / Cv -------------------------
__global__ __launch_bounds__(256) void k_dbc(
    const float* __restrict__ xs,
    const float* __restrict__ Wd, const float* __restrict__ Wb, const float* __restrict__ Wc,
    float* __restrict__ dlt, float* __restrict__ u, float* __restrict__ cv)
{
    __shared__ float As[16][68];
    __shared__ float Bs[16][68];
    float acc[4][4] = {};
    const int bx = blockIdx.x;          // 0..11
    const int wsel = bx >> 2;           // 0: delta, 1: B, 2: C
    const int n0 = (bx & 3) * 64;
    const int r0 = blockIdx.y * 64;
    const float* Bm = (wsel == 0) ? Wd : ((wsel == 1) ? Wb : Wc);
    gemm_tile_core(xs, DI, Bm, DI, DI, r0, n0, As, Bs, acc);
    const int tx = threadIdx.x & 15, ty = threadIdx.x >> 4;
#pragma unroll
    for (int i = 0; i < 4; ++i) {
        const int r = r0 + ty * 4 + i;
#pragma unroll
        for (int j = 0; j < 4; ++j) {
            const int c = n0 + tx * 4 + j;
            float v = acc[i][j];
            size_t idx = (size_t)r * DI + c;
            if (wsel == 0)      dlt[idx] = v;
            else if (wsel == 1) u[idx]   = v * xs[idx];   // Bv * xs
            else                cv[idx]  = v;
        }
    }
}

// --------------------------- kernel 3: the scan -----------------------------
// Single sequential pass. One block (128 thr = 2 waves) per (b,d); each wave
// owns an n-slice of 128 (float2 per lane). Per step:
//   dl from LDS broadcast; e = 1 + c1*dl + c2*dl^2 + c3*dl^3 (Taylor, |z|<~0.02)
//   s = e*s + dl*u ; partial p = s0*c.x + s1*c.y -> LDS
// Every 16 steps: per-wave tree reduce of its own 64 columns (4x ds_read_b128
// + adds + 2 shfl), halves combined via Yh. 16-step register double-buffered
// prefetch of u/cv rows hides L2/L3 latency.
__global__ __launch_bounds__(128) void k_scan(
    const float* __restrict__ dlt, const float* __restrict__ u,
    const float* __restrict__ cv, const float* __restrict__ A,
    float* __restrict__ y)
{
    const int tid  = threadIdx.x;
    const int lane = tid & 63;
    const int wv   = tid >> 6;          // 0..1
    const int b = blockIdx.x & 3;       // XCD-affine: one batch per XCD pair
    const int d = blockIdx.x >> 2;

    __shared__ float dls[LLEN];         // delta column for (b, :, d)
    __shared__ float P[SGRP][132];      // per-step lane partials (+pad)
    __shared__ float Yh[2][SGRP];       // per-wave half sums

    // preload delta column (strided gather, once)
    {
        const float* dp = dlt + (size_t)b * LLEN * DI + d;
#pragma unroll
        for (int k = 0; k < 4; ++k) {
            const int i = tid + 128 * k;
            dls[i] = dp[(size_t)i * DI];
        }
    }
    __syncthreads();

    // A-row slice and Taylor constants (natural exp)
    const int nf = wv * 128 + lane * 2;
    const float2 a2 = *(const float2*)(A + (size_t)d * DS + nf);
    const float c1x = a2.x, c2x = 0.5f * a2.x * a2.x, c3x = c2x * a2.x * (1.f / 3.f);
    const float c1y = a2.y, c2y = 0.5f * a2.y * a2.y, c3y = c2y * a2.y * (1.f / 3.f);

    const float2* up = (const float2*)u  + (size_t)b * LLEN * 128 + (nf >> 1);
    const float2* cp = (const float2*)cv + (size_t)b * LLEN * 128 + (nf >> 1);
    float* yo = y + (size_t)b * LLEN * DI + d;

    float s0 = 0.f, s1 = 0.f;
    float2 uA[SGRP], cA[SGRP], uB[SGRP], cB[SGRP];

#pragma unroll
    for (int i = 0; i < SGRP; ++i) {
        uA[i] = up[(size_t)i * 128];
        cA[i] = cp[(size_t)i * 128];
    }

#define PRE(UT, CT, G)                                                        \
    {                                                                         \
        _Pragma("unroll")                                                     \
        for (int i = 0; i < SGRP; ++i) {                                      \
            UT[i] = up[(size_t)((G) * SGRP + i) * 128];                       \
            CT[i] = cp[(size_t)((G) * SGRP + i) * 128];                       \
        }                                                                     \
    }

#define COMP(UT, CT, G)                                                       \
    {                                                                         \
        _Pragma("unroll")                                                     \
        for (int i = 0; i < SGRP; ++i) {                                      \
            const float dl  = dls[(G) * SGRP + i];                            \
            const float dl2 = dl * dl;                                        \
            const float dl3 = dl2 * dl;                                       \
            const float e0 = fmaf(c3x, dl3, fmaf(c2x, dl2, fmaf(c1x, dl, 1.f))); \
            const float e1 = fmaf(c3y, dl3, fmaf(c2y, dl2, fmaf(c1y, dl, 1.f))); \
            s0 = fmaf(e0, s0, dl * UT[i].x);                                  \
            s1 = fmaf(e1, s1, dl * UT[i].y);                                  \
            P[i][tid] = fmaf(s1, CT[i].y, s0 * CT[i].x);                      \
        }                                                                     \
        {   /* per-wave reduce of its own 64 columns (no cross-wave reads) */ \
            const int l = lane & 15, qq = lane >> 4;                          \
            const float* row = &P[l][wv * 64 + qq * 16];                      \
            const float4 r0 = *(const float4*)(row);                          \
            const float4 r1 = *(const float4*)(row + 4);                      \
            const float4 r2 = *(const float4*)(row + 8);                      \
            const float4 r3 = *(const float4*)(row + 12);                     \
            float sm = ((r0.x + r0.y) + (r0.z + r0.w))                        \
                     + ((r1.x + r1.y) + (r1.z + r1.w))                        \
                     + ((r2.x + r2.y) + (r2.z + r2.w))                        \
                     + ((r3.x + r3.y) + (r3.z + r3.w));                       \
            sm += __shfl_xor(sm, 16);                                         \
            sm += __shfl_xor(sm, 32);                                         \
            if (lane < 16) Yh[wv][lane] = sm;                                 \
        }                                                                     \
        __syncthreads();                                                      \
        if (tid < 16)                                                         \
            yo[(size_t)((G) * SGRP + tid) * DI] = Yh[0][tid] + Yh[1][tid];    \
        __syncthreads();                                                      \
    }

    const int NG = LLEN / SGRP;   // 32 groups
    for (int g = 0; g < NG; g += 2) {
        const int g1 = g + 1;
        const int g2 = (g + 2 < NG) ? (g + 2) : g;   // clamped (dummy) prefetch
        PRE(uB, cB, g1);
        COMP(uA, cA, g);
        PRE(uA, cA, g2);
        COMP(uB, cB, g1);
    }
#undef PRE
#undef COMP
}

// --------------------------- kernel 4: out GEMM -----------------------------
// (y * silu(z)) (M x 256) @ W_out (256 x 128) -> out (M x 128)
__global__ __launch_bounds__(256) void k_out(
    const float* __restrict__ y, const float* __restrict__ sz,
    const float* __restrict__ W_out, float* __restrict__ out)
{
    __shared__ float As[16][68];
    __shared__ float Bs[16][68];
    float acc[4][4] = {};
    const int r0 = blockIdx.y * 64;
    const int n0 = blockIdx.x * 64;
    const int tid  = threadIdx.x;
    const int arow = tid >> 2;
    const int akq  = tid & 3;
    const int bkr  = tid >> 4;
    const int bcq  = tid & 15;

    for (int k0 = 0; k0 < DI; k0 += 16) {
        size_t aoff = (size_t)(r0 + arow) * DI + k0 + akq * 4;
        float4 av  = *(const float4*)(y + aoff);
        float4 szv = *(const float4*)(sz + aoff);
        av.x *= szv.x; av.y *= szv.y; av.z *= szv.z; av.w *= szv.w;
        float4 bv = *(const float4*)(W_out + (size_t)(k0 + bkr) * DM + n0 + bcq * 4);
        __syncthreads();
        As[akq * 4 + 0][arow] = av.x;
        As[akq * 4 + 1][arow] = av.y;
        As[akq * 4 + 2][arow] = av.z;
        As[akq * 4 + 3][arow] = av.w;
        *(float4*)&Bs[bkr][bcq * 4] = bv;
        __syncthreads();
        const int tx = tid & 15, ty = tid >> 4;
#pragma unroll
        for (int kk = 0; kk < 16; ++kk) {
            float4 a = *(const float4*)&As[kk][ty * 4];
            float4 b = *(const float4*)&Bs[kk][tx * 4];
            acc[0][0] += a.x * b.x; acc[0][1] += a.x * b.y; acc[0][2] += a.x * b.z; acc[0][3] += a.x * b.w;
            acc[1][0] += a.y * b.x; acc[1][1] += a.y * b.y; acc[1][2] += a.y * b.z; acc[1][3] += a.y * b.w;
            acc[2][0] += a.z * b.x; acc[2][1] += a.z * b.y; acc[2][2] += a.z * b.z; acc[2][3] += a.z * b.w;
            acc[3][0] += a.w * b.x; acc[3][1] += a.w * b.y; acc[3][2] += a.w * b.z; acc[3][3] += a.w * b.w;
        }
    }
    const int tx = tid & 15, ty = tid >> 4;
#pragma unroll
    for (int i = 0; i < 4; ++i) {
        const int r = r0 + ty * 4 + i;
#pragma unroll
        for (int j = 0; j < 4; ++j) {
            const int c = n0 + tx * 4 + j;
            out[(size_t)r * DM + c] = acc[i][j];
        }
    }
}

// ---------------------------------------------------------------------------
extern "C" void kernel_launch(void* const* d_in, const int* in_sizes, int n_in,
                              void* d_out, int out_size, void* d_ws, size_t ws_size,
                              hipStream_t stream)
{
    const float* x       = (const float*)d_in[0];
    const float* W_in    = (const float*)d_in[1];
    const float* W_delta = (const float*)d_in[2];
    const float* W_B     = (const float*)d_in[3];
    const float* W_C     = (const float*)d_in[4];
    const float* W_out   = (const float*)d_in[5];
    const float* A       = (const float*)d_in[6];
    // d_in[7] = D, unused by the reference scan

    float* out = (float*)d_out;
    float* ws  = (float*)d_ws;

    const size_t S = (size_t)MROWS * DI;   // 2048*256 floats per plane (2 MB)
    float* xs  = ws;
    float* sz  = ws + S;
    float* dlt = ws + 2 * S;
    float* u   = ws + 3 * S;
    float* cv  = ws + 4 * S;
    float* yv  = ws + 5 * S;

    k_proj<<<dim3(8, 32), 256, 0, stream>>>(x, W_in, xs, sz);
    k_dbc <<<dim3(12, 32), 256, 0, stream>>>(xs, W_delta, W_B, W_C, dlt, u, cv);
    k_scan<<<dim3(1024), 128, 0, stream>>>(dlt, u, cv, A, yv);
    k_out <<<dim3(2, 32), 256, 0, stream>>>(yv, sz, W_out, out);
}

// Round 5
// 111.443 us; speedup vs baseline: 3.8441x; 1.0799x over previous
//
#include <hip/hip_runtime.h>
#include <hip/hip_bf16.h>

// Mamba block: B=4, L=512, D_MODEL=128, D_INNER=D_STATE=256
// proj -> (delta,Bv,Cv) -> chunked 3-pass scan (wave-private LDS, Taylor exp)
// -> out GEMM (fuses *silu(z))

#define MROWS 2048   // B*L
#define DM 128
#define DI 256
#define DS 256
#define LLEN 512
#define LC 64        // chunk length == wave size
#define NC 8         // chunks

#define LOG2E 1.44269504088896340736f

// ---------------------------------------------------------------------------
// shared fp32 GEMM tile core: 64x64 tile, K-step 16, 256 threads, 4x4/thread
// ---------------------------------------------------------------------------
__device__ __forceinline__ void gemm_tile_core(
    const float* __restrict__ A, int lda,
    const float* __restrict__ Bm, int ldb,
    int K, int r0, int n0,
    float (*__restrict__ As)[68], float (*__restrict__ Bs)[68],
    float acc[4][4])
{
    const int tid  = threadIdx.x;
    const int arow = tid >> 2;   // 0..63
    const int akq  = tid & 3;    // 0..3
    const int bkr  = tid >> 4;   // 0..15
    const int bcq  = tid & 15;   // 0..15

    for (int k0 = 0; k0 < K; k0 += 16) {
        float4 av = *(const float4*)(A + (size_t)(r0 + arow) * lda + k0 + akq * 4);
        float4 bv = *(const float4*)(Bm + (size_t)(k0 + bkr) * ldb + n0 + bcq * 4);
        __syncthreads();
        As[akq * 4 + 0][arow] = av.x;
        As[akq * 4 + 1][arow] = av.y;
        As[akq * 4 + 2][arow] = av.z;
        As[akq * 4 + 3][arow] = av.w;
        *(float4*)&Bs[bkr][bcq * 4] = bv;
        __syncthreads();
        const int tx = tid & 15, ty = tid >> 4;
#pragma unroll
        for (int kk = 0; kk < 16; ++kk) {
            float4 a = *(const float4*)&As[kk][ty * 4];
            float4 b = *(const float4*)&Bs[kk][tx * 4];
            acc[0][0] += a.x * b.x; acc[0][1] += a.x * b.y; acc[0][2] += a.x * b.z; acc[0][3] += a.x * b.w;
            acc[1][0] += a.y * b.x; acc[1][1] += a.y * b.y; acc[1][2] += a.y * b.z; acc[1][3] += a.y * b.w;
            acc[2][0] += a.z * b.x; acc[2][1] += a.z * b.y; acc[2][2] += a.z * b.z; acc[2][3] += a.z * b.w;
            acc[3][0] += a.w * b.x; acc[3][1] += a.w * b.y; acc[3][2] += a.w * b.z; acc[3][3] += a.w * b.w;
        }
    }
}

// --------------------------- kernel 1: in_proj ------------------------------
__global__ __launch_bounds__(256) void k_proj(
    const float* __restrict__ x, const float* __restrict__ W_in,
    float* __restrict__ xs, float* __restrict__ sz)
{
    __shared__ float As[16][68];
    __shared__ float Bs[16][68];
    float acc[4][4] = {};
    const int r0 = blockIdx.y * 64;
    const int n0 = blockIdx.x * 64;
    gemm_tile_core(x, DM, W_in, 2 * DI, DM, r0, n0, As, Bs, acc);
    const int tx = threadIdx.x & 15, ty = threadIdx.x >> 4;
#pragma unroll
    for (int i = 0; i < 4; ++i) {
        const int r = r0 + ty * 4 + i;
#pragma unroll
        for (int j = 0; j < 4; ++j) {
            const int c = n0 + tx * 4 + j;
            float v = acc[i][j];
            if (c < DI) {
                xs[(size_t)r * DI + c] = v;
            } else {
                float s = v / (1.f + __expf(-v));   // silu
                sz[(size_t)r * DI + (c - DI)] = s;
            }
        }
    }
}

// ------------------- kernel 2: delta / u=Bv*xs / Cv -------------------------
__global__ __launch_bounds__(256) void k_dbc(
    const float* __restrict__ xs,
    const float* __restrict__ Wd, const float* __restrict__ Wb, const float* __restrict__ Wc,
    float* __restrict__ dlt, float* __restrict__ u, float* __restrict__ cv)
{
    __shared__ float As[16][68];
    __shared__ float Bs[16][68];
    float acc[4][4] = {};
    const int bx = blockIdx.x;          // 0..11
    const int wsel = bx >> 2;           // 0: delta, 1: B, 2: C
    const int n0 = (bx & 3) * 64;
    const int r0 = blockIdx.y * 64;
    const float* Bm = (wsel == 0) ? Wd : ((wsel == 1) ? Wb : Wc);
    gemm_tile_core(xs, DI, Bm, DI, DI, r0, n0, As, Bs, acc);
    const int tx = threadIdx.x & 15, ty = threadIdx.x >> 4;
#pragma unroll
    for (int i = 0; i < 4; ++i) {
        const int r = r0 + ty * 4 + i;
#pragma unroll
        for (int j = 0; j < 4; ++j) {
            const int c = n0 + tx * 4 + j;
            float v = acc[i][j];
            size_t idx = (size_t)r * DI + c;
            if (wsel == 0)      dlt[idx] = v;
            else if (wsel == 1) u[idx]   = v * xs[idx];   // Bv * xs
            else                cv[idx]  = v;
        }
    }
}

// ------------------------ chunked scan: unit mapping ------------------------
// 8192 units = (b:4, d:256, c:8). 4 waves/block share (b, chunk), consecutive
// d -> L1 reuse of u/cv rows. b = blk&3 keeps one batch per XCD pair.
__device__ __forceinline__ void unit_map(int blk, int w, int& b, int& d, int& c)
{
    b = blk & 3;
    c = (blk >> 2) & 7;
    d = (blk >> 5) * 4 + w;
}

// Taylor-3 exp(a*dl) with per-lane precomputed c1=a, c2=a^2/2, c3=a^3/6.
// |a*dl| < ~0.05 here -> rel err < 2e-7.
#define TEXP(c1, c2, c3, dl) fmaf(fmaf(fmaf((c3), (dl), (c2)), (dl), (c1)), (dl), 1.f)

// --------------------- scan pass 1: chunk-local states ----------------------
// per (b,d,c): T_c = local scan from 0 over 64 steps; Dsum_c = sum delta.
// No barriers in the loop: dls is wave-private (same-wave LDS is in-order).
__global__ __launch_bounds__(256) void k_scan1(
    const float* __restrict__ dlt, const float* __restrict__ u,
    const float* __restrict__ A,
    float* __restrict__ tc, float* __restrict__ dsum)
{
    const int lane = threadIdx.x & 63;
    const int w    = threadIdx.x >> 6;
    int b, d, c;
    unit_map(blockIdx.x, w, b, d, c);

    __shared__ float dls[4][LC];

    const size_t base = (size_t)b * LLEN * DI + (size_t)c * LC * DI;

    // preload delta column slice (one element per lane) + Dsum butterfly
    const float dlv = dlt[base + (size_t)lane * DI + d];
    dls[w][lane] = dlv;
    float ds_ = dlv;
#pragma unroll
    for (int off = 32; off > 0; off >>= 1)
        ds_ += __shfl_xor(ds_, off);
    __syncthreads();   // once, safety

    // A-row slice, Taylor constants (natural exp)
    float4 a4 = *(const float4*)(A + (size_t)d * DS + lane * 4);
    const float c1x = a4.x, c2x = 0.5f * a4.x * a4.x, c3x = c2x * a4.x * (1.f / 3.f);
    const float c1y = a4.y, c2y = 0.5f * a4.y * a4.y, c3y = c2y * a4.y * (1.f / 3.f);
    const float c1z = a4.z, c2z = 0.5f * a4.z * a4.z, c3z = c2z * a4.z * (1.f / 3.f);
    const float c1w = a4.w, c2w = 0.5f * a4.w * a4.w, c3w = c2w * a4.w * (1.f / 3.f);

    const float4* up = (const float4*)(u + base) + lane;

    float4 s = make_float4(0.f, 0.f, 0.f, 0.f);
#pragma unroll 16
    for (int l = 0; l < LC; ++l) {
        const float  dl = dls[w][l];
        const float4 uv = up[(size_t)l * 64];
        s.x = fmaf(TEXP(c1x, c2x, c3x, dl), s.x, dl * uv.x);
        s.y = fmaf(TEXP(c1y, c2y, c3y, dl), s.y, dl * uv.y);
        s.z = fmaf(TEXP(c1z, c2z, c3z, dl), s.z, dl * uv.z);
        s.w = fmaf(TEXP(c1w, c2w, c3w, dl), s.w, dl * uv.w);
    }

    const size_t rb = ((size_t)(b * 256 + d)) * NC + c;
    *(float4*)(tc + rb * 256 + lane * 4) = s;
    if (lane == 0) dsum[rb] = ds_;
}

// ------------------- scan pass 2: combine chunk boundaries ------------------
// sequential over 8 chunks; writes s_init[c] in place over tc.
__global__ __launch_bounds__(256) void k_scan2(
    const float* __restrict__ A, float* __restrict__ tc,
    const float* __restrict__ dsum)
{
    const int lane = threadIdx.x & 63;
    const int w    = threadIdx.x >> 6;
    const int blk  = blockIdx.x;
    const int b = blk & 3;
    const int d = (blk >> 2) * 4 + w;

    float4 a4 = *(const float4*)(A + (size_t)d * DS + lane * 4);
    a4.x *= LOG2E; a4.y *= LOG2E; a4.z *= LOG2E; a4.w *= LOG2E;

    const size_t rb = ((size_t)(b * 256 + d)) * NC;
    float4 s = make_float4(0.f, 0.f, 0.f, 0.f);
#pragma unroll
    for (int c = 0; c < NC; ++c) {
        float* p = tc + (rb + c) * 256 + lane * 4;
        float4 T = *(const float4*)p;
        float  Dc = dsum[rb + c];
        *(float4*)p = s;                      // s_init[c]
        s.x = exp2f(a4.x * Dc) * s.x + T.x;
        s.y = exp2f(a4.y * Dc) * s.y + T.y;
        s.z = exp2f(a4.z * Dc) * s.z + T.z;
        s.w = exp2f(a4.w * Dc) * s.w + T.w;
    }
}

// ------------------- scan pass 3: outputs from s_init -----------------------
// 16 step-partials accumulate in registers; per group of 16 steps one
// wave-private LDS transpose T[64][17] (odd stride -> 2-way = free) gives
// y[l] without butterflies. No barriers in the loop.
__global__ __launch_bounds__(256) void k_scan3(
    const float* __restrict__ dlt, const float* __restrict__ u,
    const float* __restrict__ cv, const float* __restrict__ A,
    const float* __restrict__ tc, float* __restrict__ y)
{
    const int lane = threadIdx.x & 63;
    const int w    = threadIdx.x >> 6;
    int b, d, c;
    unit_map(blockIdx.x, w, b, d, c);

    __shared__ float dls[4][LC];
    __shared__ float T[4][LC][17];

    const size_t base = (size_t)b * LLEN * DI + (size_t)c * LC * DI;

    dls[w][lane] = dlt[base + (size_t)lane * DI + d];
    __syncthreads();   // once, safety

    float4 a4 = *(const float4*)(A + (size_t)d * DS + lane * 4);
    const float c1x = a4.x, c2x = 0.5f * a4.x * a4.x, c3x = c2x * a4.x * (1.f / 3.f);
    const float c1y = a4.y, c2y = 0.5f * a4.y * a4.y, c3y = c2y * a4.y * (1.f / 3.f);
    const float c1z = a4.z, c2z = 0.5f * a4.z * a4.z, c3z = c2z * a4.z * (1.f / 3.f);
    const float c1w = a4.w, c2w = 0.5f * a4.w * a4.w, c3w = c2w * a4.w * (1.f / 3.f);

    const float4* up = (const float4*)(u + base) + lane;
    const float4* cp = (const float4*)(cv + base) + lane;
    float* yo = y + base + d;

    const size_t rb = ((size_t)(b * 256 + d)) * NC + c;
    float4 s = *(const float4*)(tc + rb * 256 + lane * 4);

    const int col = lane & 15, seg = lane >> 4;

    for (int g = 0; g < 4; ++g) {
        float p[16];
#pragma unroll
        for (int i = 0; i < 16; ++i) {
            const int l = g * 16 + i;
            const float  dl = dls[w][l];
            const float4 uv = up[(size_t)l * 64];
            const float4 cV = cp[(size_t)l * 64];
            s.x = fmaf(TEXP(c1x, c2x, c3x, dl), s.x, dl * uv.x);
            s.y = fmaf(TEXP(c1y, c2y, c3y, dl), s.y, dl * uv.y);
            s.z = fmaf(TEXP(c1z, c2z, c3z, dl), s.z, dl * uv.z);
            s.w = fmaf(TEXP(c1w, c2w, c3w, dl), s.w, dl * uv.w);
            p[i] = fmaf(s.w, cV.w, fmaf(s.z, cV.z, fmaf(s.y, cV.y, s.x * cV.x)));
        }
        // wave-private transpose: row = lane, 4x ds_write_b128
        float* tr = &T[w][lane][0];
        *(float4*)(tr + 0)  = make_float4(p[0],  p[1],  p[2],  p[3]);
        *(float4*)(tr + 4)  = make_float4(p[4],  p[5],  p[6],  p[7]);
        *(float4*)(tr + 8)  = make_float4(p[8],  p[9],  p[10], p[11]);
        *(float4*)(tr + 12) = make_float4(p[12], p[13], p[14], p[15]);
        // reduce: 4 lanes per column, 16 rows each
        float sm = 0.f;
#pragma unroll
        for (int r = 0; r < 16; ++r)
            sm += T[w][seg * 16 + r][col];
        sm += __shfl_xor(sm, 16);
        sm += __shfl_xor(sm, 32);
        if (lane < 16)
            yo[(size_t)(g * 16 + lane) * DI] = sm;
    }
}

// --------------------------- kernel 4: out GEMM -----------------------------
// (y * silu(z)) (M x 256) @ W_out (256 x 128) -> out (M x 128)
__global__ __launch_bounds__(256) void k_out(
    const float* __restrict__ y, const float* __restrict__ sz,
    const float* __restrict__ W_out, float* __restrict__ out)
{
    __shared__ float As[16][68];
    __shared__ float Bs[16][68];
    float acc[4][4] = {};
    const int r0 = blockIdx.y * 64;
    const int n0 = blockIdx.x * 64;
    const int tid  = threadIdx.x;
    const int arow = tid >> 2;
    const int akq  = tid & 3;
    const int bkr  = tid >> 4;
    const int bcq  = tid & 15;

    for (int k0 = 0; k0 < DI; k0 += 16) {
        size_t aoff = (size_t)(r0 + arow) * DI + k0 + akq * 4;
        float4 av  = *(const float4*)(y + aoff);
        float4 szv = *(const float4*)(sz + aoff);
        av.x *= szv.x; av.y *= szv.y; av.z *= szv.z; av.w *= szv.w;
        float4 bv = *(const float4*)(W_out + (size_t)(k0 + bkr) * DM + n0 + bcq * 4);
        __syncthreads();
        As[akq * 4 + 0][arow] = av.x;
        As[akq * 4 + 1][arow] = av.y;
        As[akq * 4 + 2][arow] = av.z;
        As[akq * 4 + 3][arow] = av.w;
        *(float4*)&Bs[bkr][bcq * 4] = bv;
        __syncthreads();
        const int tx = tid & 15, ty = tid >> 4;
#pragma unroll
        for (int kk = 0; kk < 16; ++kk) {
            float4 a = *(const float4*)&As[kk][ty * 4];
            float4 b = *(const float4*)&Bs[kk][tx * 4];
            acc[0][0] += a.x * b.x; acc[0][1] += a.x * b.y; acc[0][2] += a.x * b.z; acc[0][3] += a.x * b.w;
            acc[1][0] += a.y * b.x; acc[1][1] += a.y * b.y; acc[1][2] += a.y * b.z; acc[1][3] += a.y * b.w;
            acc[2][0] += a.z * b.x; acc[2][1] += a.z * b.y; acc[2][2] += a.z * b.z; acc[2][3] += a.z * b.w;
            acc[3][0] += a.w * b.x; acc[3][1] += a.w * b.y; acc[3][2] += a.w * b.z; acc[3][3] += a.w * b.w;
        }
    }
    const int tx = tid & 15, ty = tid >> 4;
#pragma unroll
    for (int i = 0; i < 4; ++i) {
        const int r = r0 + ty * 4 + i;
#pragma unroll
        for (int j = 0; j < 4; ++j) {
            const int c = n0 + tx * 4 + j;
            out[(size_t)r * DM + c] = acc[i][j];
        }
    }
}

// ---------------------------------------------------------------------------
extern "C" void kernel_launch(void* const* d_in, const int* in_sizes, int n_in,
                              void* d_out, int out_size, void* d_ws, size_t ws_size,
                              hipStream_t stream)
{
    const float* x       = (const float*)d_in[0];
    const float* W_in    = (const float*)d_in[1];
    const float* W_delta = (const float*)d_in[2];
    const float* W_B     = (const float*)d_in[3];
    const float* W_C     = (const float*)d_in[4];
    const float* W_out   = (const float*)d_in[5];
    const float* A       = (const float*)d_in[6];
    // d_in[7] = D, unused by the reference scan

    float* out = (float*)d_out;
    float* ws  = (float*)d_ws;

    const size_t S = (size_t)MROWS * DI;   // 2048*256 floats per plane (2 MB)
    float* xs  = ws;
    float* sz  = ws + S;
    float* dlt = ws + 2 * S;
    float* u   = ws + 3 * S;
    float* cv  = ws + 4 * S;
    float* yv  = ws + 5 * S;
    float* tc  = ws + 6 * S;               // 1024*8*256 floats = 8 MB
    float* dsm = ws + 6 * S + (size_t)1024 * NC * 256;  // 32 KB

    k_proj <<<dim3(8, 32), 256, 0, stream>>>(x, W_in, xs, sz);
    k_dbc  <<<dim3(12, 32), 256, 0, stream>>>(xs, W_delta, W_B, W_C, dlt, u, cv);
    k_scan1<<<dim3(2048), 256, 0, stream>>>(dlt, u, A, tc, dsm);
    k_scan2<<<dim3(256),  256, 0, stream>>>(A, tc, dsm);
    k_scan3<<<dim3(2048), 256, 0, stream>>>(dlt, u, cv, A, tc, yv);
    k_out  <<<dim3(2, 32), 256, 0, stream>>>(yv, sz, W_out, out);
}

// Round 6
// 99.700 us; speedup vs baseline: 4.2969x; 1.1178x over previous
//
#include <hip/hip_runtime.h>
#include <hip/hip_bf16.h>

// Mamba block: B=4, L=512, D_MODEL=128, D_INNER=D_STATE=256
// proj -> (delta,Bv,Cv) -> chunked 3-pass scan (D_REP=4 per wave, Taylor exp,
// wave-private LDS transpose) -> out GEMM (fuses *silu(z))

#define MROWS 2048   // B*L
#define DM 128
#define DI 256
#define DS 256
#define LLEN 512
#define LC 64        // chunk length
#define NC 8         // chunks

#define LOG2E 1.44269504088896340736f

// Taylor-3 exp(a*dl), Horner: per-lane consts c1=a, c2=a^2/2, c3=a^3/6.
// |a*dl| < ~0.05 here -> rel err < 2e-7.
#define TEXP(c1, c2, c3, dl) fmaf(fmaf(fmaf((c3), (dl), (c2)), (dl), (c1)), (dl), 1.f)

// ---------------------------------------------------------------------------
// shared fp32 GEMM tile core: 64x64 tile, K-step 16, 256 threads, 4x4/thread
// ---------------------------------------------------------------------------
__device__ __forceinline__ void gemm_tile_core(
    const float* __restrict__ A, int lda,
    const float* __restrict__ Bm, int ldb,
    int K, int r0, int n0,
    float (*__restrict__ As)[68], float (*__restrict__ Bs)[68],
    float acc[4][4])
{
    const int tid  = threadIdx.x;
    const int arow = tid >> 2;   // 0..63
    const int akq  = tid & 3;    // 0..3
    const int bkr  = tid >> 4;   // 0..15
    const int bcq  = tid & 15;   // 0..15

    for (int k0 = 0; k0 < K; k0 += 16) {
        float4 av = *(const float4*)(A + (size_t)(r0 + arow) * lda + k0 + akq * 4);
        float4 bv = *(const float4*)(Bm + (size_t)(k0 + bkr) * ldb + n0 + bcq * 4);
        __syncthreads();
        As[akq * 4 + 0][arow] = av.x;
        As[akq * 4 + 1][arow] = av.y;
        As[akq * 4 + 2][arow] = av.z;
        As[akq * 4 + 3][arow] = av.w;
        *(float4*)&Bs[bkr][bcq * 4] = bv;
        __syncthreads();
        const int tx = tid & 15, ty = tid >> 4;
#pragma unroll
        for (int kk = 0; kk < 16; ++kk) {
            float4 a = *(const float4*)&As[kk][ty * 4];
            float4 b = *(const float4*)&Bs[kk][tx * 4];
            acc[0][0] += a.x * b.x; acc[0][1] += a.x * b.y; acc[0][2] += a.x * b.z; acc[0][3] += a.x * b.w;
            acc[1][0] += a.y * b.x; acc[1][1] += a.y * b.y; acc[1][2] += a.y * b.z; acc[1][3] += a.y * b.w;
            acc[2][0] += a.z * b.x; acc[2][1] += a.z * b.y; acc[2][2] += a.z * b.z; acc[2][3] += a.z * b.w;
            acc[3][0] += a.w * b.x; acc[3][1] += a.w * b.y; acc[3][2] += a.w * b.z; acc[3][3] += a.w * b.w;
        }
    }
}

// --------------------------- kernel 1: in_proj ------------------------------
__global__ __launch_bounds__(256) void k_proj(
    const float* __restrict__ x, const float* __restrict__ W_in,
    float* __restrict__ xs, float* __restrict__ sz)
{
    __shared__ float As[16][68];
    __shared__ float Bs[16][68];
    float acc[4][4] = {};
    const int r0 = blockIdx.y * 64;
    const int n0 = blockIdx.x * 64;
    gemm_tile_core(x, DM, W_in, 2 * DI, DM, r0, n0, As, Bs, acc);
    const int tx = threadIdx.x & 15, ty = threadIdx.x >> 4;
#pragma unroll
    for (int i = 0; i < 4; ++i) {
        const int r = r0 + ty * 4 + i;
#pragma unroll
        for (int j = 0; j < 4; ++j) {
            const int c = n0 + tx * 4 + j;
            float v = acc[i][j];
            if (c < DI) {
                xs[(size_t)r * DI + c] = v;
            } else {
                float s = v / (1.f + __expf(-v));   // silu
                sz[(size_t)r * DI + (c - DI)] = s;
            }
        }
    }
}

// ------------------- kernel 2: delta / u=Bv*xs / Cv -------------------------
__global__ __launch_bounds__(256) void k_dbc(
    const float* __restrict__ xs,
    const float* __restrict__ Wd, const float* __restrict__ Wb, const float* __restrict__ Wc,
    float* __restrict__ dlt, float* __restrict__ u, float* __restrict__ cv)
{
    __shared__ float As[16][68];
    __shared__ float Bs[16][68];
    float acc[4][4] = {};
    const int bx = blockIdx.x;          // 0..11
    const int wsel = bx >> 2;           // 0: delta, 1: B, 2: C
    const int n0 = (bx & 3) * 64;
    const int r0 = blockIdx.y * 64;
    const float* Bm = (wsel == 0) ? Wd : ((wsel == 1) ? Wb : Wc);
    gemm_tile_core(xs, DI, Bm, DI, DI, r0, n0, As, Bs, acc);
    const int tx = threadIdx.x & 15, ty = threadIdx.x >> 4;
#pragma unroll
    for (int i = 0; i < 4; ++i) {
        const int r = r0 + ty * 4 + i;
#pragma unroll
        for (int j = 0; j < 4; ++j) {
            const int c = n0 + tx * 4 + j;
            float v = acc[i][j];
            size_t idx = (size_t)r * DI + c;
            if (wsel == 0)      dlt[idx] = v;
            else if (wsel == 1) u[idx]   = v * xs[idx];   // Bv * xs
            else                cv[idx]  = v;
        }
    }
}

// ------------------------ chunked scan: unit mapping ------------------------
// wave-units = (b:4, c:8, dq:64) with 4 d's per wave. 4 waves/block share
// (b,c) -> L1 reuse of u/cv rows; b = blk&3 keeps one batch per XCD pair.
// blocks = 512, threads = 256 (4 waves).

// --------------------- scan pass 1: chunk-local states ----------------------
__global__ __launch_bounds__(256) void k_scan1(
    const float* __restrict__ dlt, const float* __restrict__ u,
    const float* __restrict__ A,
    float* __restrict__ tc, float* __restrict__ dsum)
{
    const int lane = threadIdx.x & 63;
    const int w    = threadIdx.x >> 6;
    const int blk  = blockIdx.x;
    const int b  = blk & 3;
    const int c  = (blk >> 2) & 7;
    const int d0 = ((blk >> 5) * 4 + w) * 4;

    __shared__ float dls[4][4][LC];   // [wave][dd][l]

    const size_t base = (size_t)b * LLEN * DI + (size_t)c * LC * DI;

    // stage delta rows (4 consecutive d's -> one float4 per lane) + Dsum
    float4 dv = *(const float4*)(dlt + base + (size_t)lane * DI + d0);
    dls[0 + w][0][lane] = dv.x;   // (indexing via w below)
    dls[w][0][lane] = dv.x;
    dls[w][1][lane] = dv.y;
    dls[w][2][lane] = dv.z;
    dls[w][3][lane] = dv.w;
    float dsv[4] = { dv.x, dv.y, dv.z, dv.w };
#pragma unroll
    for (int dd = 0; dd < 4; ++dd) {
#pragma unroll
        for (int off = 32; off > 0; off >>= 1)
            dsv[dd] += __shfl_xor(dsv[dd], off);
    }
    __syncthreads();

    // Taylor consts for the 4 d rows
    float4 c1[4], c2[4], c3[4];
#pragma unroll
    for (int dd = 0; dd < 4; ++dd) {
        float4 a = *(const float4*)(A + (size_t)(d0 + dd) * DS + lane * 4);
        c1[dd] = a;
        c2[dd] = make_float4(0.5f * a.x * a.x, 0.5f * a.y * a.y,
                             0.5f * a.z * a.z, 0.5f * a.w * a.w);
        c3[dd] = make_float4(c2[dd].x * a.x * (1.f / 3.f), c2[dd].y * a.y * (1.f / 3.f),
                             c2[dd].z * a.z * (1.f / 3.f), c2[dd].w * a.w * (1.f / 3.f));
    }

    const float4* up = (const float4*)(u + base) + lane;
    float4 s[4] = {};
    float4 ub[2][4];

#define S1_PRE(NXT, G1)                                                       \
    {                                                                         \
        _Pragma("unroll")                                                     \
        for (int i = 0; i < 4; ++i)                                           \
            ub[NXT][i] = up[(size_t)((G1) * 4 + i) * 64];                     \
    }

#define S1_STEP4(CUR, G)                                                      \
    {                                                                         \
        _Pragma("unroll")                                                     \
        for (int i0 = 0; i0 < 4; ++i0) {                                      \
            const int l = (G) * 4 + i0;                                       \
            const float4 uv = ub[CUR][i0];                                    \
            _Pragma("unroll")                                                 \
            for (int dd = 0; dd < 4; ++dd) {                                  \
                const float dl = dls[w][dd][l];                               \
                s[dd].x = fmaf(TEXP(c1[dd].x, c2[dd].x, c3[dd].x, dl), s[dd].x, dl * uv.x); \
                s[dd].y = fmaf(TEXP(c1[dd].y, c2[dd].y, c3[dd].y, dl), s[dd].y, dl * uv.y); \
                s[dd].z = fmaf(TEXP(c1[dd].z, c2[dd].z, c3[dd].z, dl), s[dd].z, dl * uv.z); \
                s[dd].w = fmaf(TEXP(c1[dd].w, c2[dd].w, c3[dd].w, dl), s[dd].w, dl * uv.w); \
            }                                                                 \
        }                                                                     \
    }

    S1_PRE(0, 0)
    for (int g2 = 0; g2 < 8; ++g2) {
        S1_PRE(1, g2 * 2 + 1)
        S1_STEP4(0, g2 * 2)
        if (g2 < 7) S1_PRE(0, g2 * 2 + 2)
        S1_STEP4(1, g2 * 2 + 1)
    }
#undef S1_PRE
#undef S1_STEP4

    const size_t rbb = ((size_t)(b * 256 + d0)) * NC + c;
#pragma unroll
    for (int dd = 0; dd < 4; ++dd) {
        *(float4*)(tc + (rbb + (size_t)dd * NC) * 256 + lane * 4) = s[dd];
        if (lane == 0) dsum[rbb + dd * NC] = dsv[dd];
    }
}

// ------------------- scan pass 2: combine chunk boundaries ------------------
__global__ __launch_bounds__(256) void k_scan2(
    const float* __restrict__ A, float* __restrict__ tc,
    const float* __restrict__ dsum)
{
    const int lane = threadIdx.x & 63;
    const int w    = threadIdx.x >> 6;
    const int blk  = blockIdx.x;
    const int b = blk & 3;
    const int d = (blk >> 2) * 4 + w;

    float4 a4 = *(const float4*)(A + (size_t)d * DS + lane * 4);
    a4.x *= LOG2E; a4.y *= LOG2E; a4.z *= LOG2E; a4.w *= LOG2E;

    const size_t rb = ((size_t)(b * 256 + d)) * NC;
    float4 s = make_float4(0.f, 0.f, 0.f, 0.f);
#pragma unroll
    for (int c = 0; c < NC; ++c) {
        float* p = tc + (rb + c) * 256 + lane * 4;
        float4 T = *(const float4*)p;
        float  Dc = dsum[rb + c];
        *(float4*)p = s;                      // s_init[c]
        s.x = exp2f(a4.x * Dc) * s.x + T.x;
        s.y = exp2f(a4.y * Dc) * s.y + T.y;
        s.z = exp2f(a4.z * Dc) * s.z + T.z;
        s.w = exp2f(a4.w * Dc) * s.w + T.w;
    }
}

// ------------------- scan pass 3: outputs from s_init -----------------------
// 4 d per wave; per-8-step wave-private LDS transpose T[64][33] (odd stride,
// 2-way = free) reduces 32 (l,d) columns; no in-loop cross-wave dependencies.
__global__ __launch_bounds__(256) void k_scan3(
    const float* __restrict__ dlt, const float* __restrict__ u,
    const float* __restrict__ cv, const float* __restrict__ A,
    const float* __restrict__ tc, float* __restrict__ y)
{
    const int lane = threadIdx.x & 63;
    const int w    = threadIdx.x >> 6;
    const int blk  = blockIdx.x;
    const int b  = blk & 3;
    const int c  = (blk >> 2) & 7;
    const int d0 = ((blk >> 5) * 4 + w) * 4;

    __shared__ float dls[4][4][LC];   // [wave][dd][l]
    __shared__ float T[4][LC][33];    // [wave][row=lane][col=dd*8+i]

    const size_t base = (size_t)b * LLEN * DI + (size_t)c * LC * DI;

    float4 dv = *(const float4*)(dlt + base + (size_t)lane * DI + d0);
    dls[w][0][lane] = dv.x;
    dls[w][1][lane] = dv.y;
    dls[w][2][lane] = dv.z;
    dls[w][3][lane] = dv.w;
    __syncthreads();

    float4 c1[4], c2[4], c3[4];
#pragma unroll
    for (int dd = 0; dd < 4; ++dd) {
        float4 a = *(const float4*)(A + (size_t)(d0 + dd) * DS + lane * 4);
        c1[dd] = a;
        c2[dd] = make_float4(0.5f * a.x * a.x, 0.5f * a.y * a.y,
                             0.5f * a.z * a.z, 0.5f * a.w * a.w);
        c3[dd] = make_float4(c2[dd].x * a.x * (1.f / 3.f), c2[dd].y * a.y * (1.f / 3.f),
                             c2[dd].z * a.z * (1.f / 3.f), c2[dd].w * a.w * (1.f / 3.f));
    }

    const float4* up = (const float4*)(u + base) + lane;
    const float4* cp = (const float4*)(cv + base) + lane;
    float* yb = y + base;

    const size_t rbb = ((size_t)(b * 256 + d0)) * NC + c;
    float4 s[4];
#pragma unroll
    for (int dd = 0; dd < 4; ++dd)
        s[dd] = *(const float4*)(tc + (rbb + (size_t)dd * NC) * 256 + lane * 4);

    float4 ub[2][4], cb[2][4];
    float  p[4][8];

#define S3_PRE(NXT, G1)                                                       \
    {                                                                         \
        _Pragma("unroll")                                                     \
        for (int i = 0; i < 4; ++i) {                                         \
            ub[NXT][i] = up[(size_t)((G1) * 4 + i) * 64];                     \
            cb[NXT][i] = cp[(size_t)((G1) * 4 + i) * 64];                     \
        }                                                                     \
    }

#define S3_STEP4(CUR, G, PBASE)                                               \
    {                                                                         \
        _Pragma("unroll")                                                     \
        for (int i0 = 0; i0 < 4; ++i0) {                                      \
            const int l = (G) * 4 + i0;                                       \
            const float4 uv = ub[CUR][i0];                                    \
            const float4 cV = cb[CUR][i0];                                    \
            _Pragma("unroll")                                                 \
            for (int dd = 0; dd < 4; ++dd) {                                  \
                const float dl = dls[w][dd][l];                               \
                s[dd].x = fmaf(TEXP(c1[dd].x, c2[dd].x, c3[dd].x, dl), s[dd].x, dl * uv.x); \
                s[dd].y = fmaf(TEXP(c1[dd].y, c2[dd].y, c3[dd].y, dl), s[dd].y, dl * uv.y); \
                s[dd].z = fmaf(TEXP(c1[dd].z, c2[dd].z, c3[dd].z, dl), s[dd].z, dl * uv.z); \
                s[dd].w = fmaf(TEXP(c1[dd].w, c2[dd].w, c3[dd].w, dl), s[dd].w, dl * uv.w); \
                p[dd][(PBASE) + i0] =                                         \
                    fmaf(s[dd].w, cV.w, fmaf(s[dd].z, cV.z,                   \
                         fmaf(s[dd].y, cV.y, s[dd].x * cV.x)));               \
            }                                                                 \
        }                                                                     \
    }

#define S3_FLUSH(GODD)                                                        \
    {                                                                         \
        float* tr = &T[w][lane][0];                                           \
        _Pragma("unroll")                                                     \
        for (int dd = 0; dd < 4; ++dd) {                                      \
            *(float4*)(tr + dd * 8)     = make_float4(p[dd][0], p[dd][1], p[dd][2], p[dd][3]); \
            *(float4*)(tr + dd * 8 + 4) = make_float4(p[dd][4], p[dd][5], p[dd][6], p[dd][7]); \
        }                                                                     \
        const int cc = lane & 31, seg = lane >> 5;                            \
        float sm = 0.f;                                                       \
        _Pragma("unroll")                                                     \
        for (int r = 0; r < 32; ++r)                                          \
            sm += T[w][seg * 32 + r][cc];                                     \
        sm += __shfl_xor(sm, 32);                                             \
        if (lane < 32)                                                        \
            yb[(size_t)(((GODD) - 1) * 4 + (cc & 7)) * DI + d0 + (cc >> 3)] = sm; \
    }

    S3_PRE(0, 0)
    for (int g2 = 0; g2 < 8; ++g2) {
        S3_PRE(1, g2 * 2 + 1)
        S3_STEP4(0, g2 * 2, 0)
        if (g2 < 7) S3_PRE(0, g2 * 2 + 2)
        S3_STEP4(1, g2 * 2 + 1, 4)
        S3_FLUSH(g2 * 2 + 1)
        if ((g2 & 1) == 1) __syncthreads();   // re-converge every 16 steps (L1 reuse)
    }
#undef S3_PRE
#undef S3_STEP4
#undef S3_FLUSH
}

// --------------------------- kernel 4: out GEMM -----------------------------
// (y * silu(z)) (M x 256) @ W_out (256 x 128) -> out (M x 128)
__global__ __launch_bounds__(256) void k_out(
    const float* __restrict__ y, const float* __restrict__ sz,
    const float* __restrict__ W_out, float* __restrict__ out)
{
    __shared__ float As[16][68];
    __shared__ float Bs[16][68];
    float acc[4][4] = {};
    const int r0 = blockIdx.y * 64;
    const int n0 = blockIdx.x * 64;
    const int tid  = threadIdx.x;
    const int arow = tid >> 2;
    const int akq  = tid & 3;
    const int bkr  = tid >> 4;
    const int bcq  = tid & 15;

    for (int k0 = 0; k0 < DI; k0 += 16) {
        size_t aoff = (size_t)(r0 + arow) * DI + k0 + akq * 4;
        float4 av  = *(const float4*)(y + aoff);
        float4 szv = *(const float4*)(sz + aoff);
        av.x *= szv.x; av.y *= szv.y; av.z *= szv.z; av.w *= szv.w;
        float4 bv = *(const float4*)(W_out + (size_t)(k0 + bkr) * DM + n0 + bcq * 4);
        __syncthreads();
        As[akq * 4 + 0][arow] = av.x;
        As[akq * 4 + 1][arow] = av.y;
        As[akq * 4 + 2][arow] = av.z;
        As[akq * 4 + 3][arow] = av.w;
        *(float4*)&Bs[bkr][bcq * 4] = bv;
        __syncthreads();
        const int tx = tid & 15, ty = tid >> 4;
#pragma unroll
        for (int kk = 0; kk < 16; ++kk) {
            float4 a = *(const float4*)&As[kk][ty * 4];
            float4 b = *(const float4*)&Bs[kk][tx * 4];
            acc[0][0] += a.x * b.x; acc[0][1] += a.x * b.y; acc[0][2] += a.x * b.z; acc[0][3] += a.x * b.w;
            acc[1][0] += a.y * b.x; acc[1][1] += a.y * b.y; acc[1][2] += a.y * b.z; acc[1][3] += a.y * b.w;
            acc[2][0] += a.z * b.x; acc[2][1] += a.z * b.y; acc[2][2] += a.z * b.z; acc[2][3] += a.z * b.w;
            acc[3][0] += a.w * b.x; acc[3][1] += a.w * b.y; acc[3][2] += a.w * b.z; acc[3][3] += a.w * b.w;
        }
    }
    const int tx = tid & 15, ty = tid >> 4;
#pragma unroll
    for (int i = 0; i < 4; ++i) {
        const int r = r0 + ty * 4 + i;
#pragma unroll
        for (int j = 0; j < 4; ++j) {
            const int c = n0 + tx * 4 + j;
            out[(size_t)r * DM + c] = acc[i][j];
        }
    }
}

// ---------------------------------------------------------------------------
extern "C" void kernel_launch(void* const* d_in, const int* in_sizes, int n_in,
                              void* d_out, int out_size, void* d_ws, size_t ws_size,
                              hipStream_t stream)
{
    const float* x       = (const float*)d_in[0];
    const float* W_in    = (const float*)d_in[1];
    const float* W_delta = (const float*)d_in[2];
    const float* W_B     = (const float*)d_in[3];
    const float* W_C     = (const float*)d_in[4];
    const float* W_out   = (const float*)d_in[5];
    const float* A       = (const float*)d_in[6];
    // d_in[7] = D, unused by the reference scan

    float* out = (float*)d_out;
    float* ws  = (float*)d_ws;

    const size_t S = (size_t)MROWS * DI;   // 2048*256 floats per plane (2 MB)
    float* xs  = ws;
    float* sz  = ws + S;
    float* dlt = ws + 2 * S;
    float* u   = ws + 3 * S;
    float* cv  = ws + 4 * S;
    float* yv  = ws + 5 * S;
    float* tc  = ws + 6 * S;               // 1024*8*256 floats = 8 MB
    float* dsm = ws + 6 * S + (size_t)1024 * NC * 256;  // 32 KB

    k_proj <<<dim3(8, 32), 256, 0, stream>>>(x, W_in, xs, sz);
    k_dbc  <<<dim3(12, 32), 256, 0, stream>>>(xs, W_delta, W_B, W_C, dlt, u, cv);
    k_scan1<<<dim3(512), 256, 0, stream>>>(dlt, u, A, tc, dsm);
    k_scan2<<<dim3(256), 256, 0, stream>>>(A, tc, dsm);
    k_scan3<<<dim3(512), 256, 0, stream>>>(dlt, u, cv, A, tc, yv);
    k_out  <<<dim3(2, 32), 256, 0, stream>>>(yv, sz, W_out, out);
}

// Round 7
// 76.541 us; speedup vs baseline: 5.5971x; 1.3026x over previous
//
#include <hip/hip_runtime.h>
#include <hip/hip_bf16.h>

// Mamba block: B=4, L=512, D_MODEL=128, D_INNER=D_STATE=256
// prep(bf16+transpose) -> MFMA proj -> MFMA dbc -> chunked 3-pass scan
// (D_REP=4, Taylor exp) -> MFMA out GEMM (fuses *silu(z))

#define MROWS 2048   // B*L
#define DM 128
#define DI 256
#define DS 256
#define LLEN 512
#define LC 64        // chunk length
#define NC 8         // chunks

#define LOG2E 1.44269504088896340736f

typedef short bf16x8 __attribute__((ext_vector_type(8)));
typedef float f32x4  __attribute__((ext_vector_type(4)));

__device__ __forceinline__ short f2bf(float f) {
    union { float f; unsigned u; } v; v.f = f;
    unsigned r = v.u + 0x7FFFu + ((v.u >> 16) & 1u);   // RNE
    return (short)(r >> 16);
}

// Taylor-3 exp(a*dl), Horner: per-lane consts c1=a, c2=a^2/2, c3=a^3/6.
#define TEXP(c1, c2, c3, dl) fmaf(fmaf(fmaf((c3), (dl), (c2)), (dl), (c1)), (dl), 1.f)

// ---------------------------------------------------------------------------
// kernel 0: prep — x -> bf16; weights -> bf16 transposed (N-major)
// blocks: [0,128) x-convert; [128,192) W_in; [192,256) Wd; [256,320) Wb;
//         [320,384) Wc; [384,416) W_out
// ---------------------------------------------------------------------------
__device__ __forceinline__ void tconv(float (*tile)[33],
                                      const float* __restrict__ src,
                                      short* __restrict__ dst,
                                      int Ms, int Ns, int ti, int tj, int tid)
{
    const int r = tid >> 5, c = tid & 31;
#pragma unroll
    for (int i = 0; i < 4; ++i)
        tile[r + 8 * i][c] = src[(size_t)(ti * 32 + r + 8 * i) * Ns + tj * 32 + c];
    __syncthreads();
#pragma unroll
    for (int i = 0; i < 4; ++i)
        dst[(size_t)(tj * 32 + r + 8 * i) * Ms + ti * 32 + c] = f2bf(tile[c][r + 8 * i]);
}

__global__ __launch_bounds__(256) void k_prep(
    const float* __restrict__ x, const float* __restrict__ W_in,
    const float* __restrict__ Wd, const float* __restrict__ Wb,
    const float* __restrict__ Wc, const float* __restrict__ W_out,
    short* __restrict__ x_bf, short* __restrict__ W_inT,
    short* __restrict__ WdbcT, short* __restrict__ W_outT)
{
    __shared__ float tile[32][33];
    const int bid = blockIdx.x;
    const int t = threadIdx.x;
    if (bid < 128) {                     // x -> bf16 elementwise
        const size_t base = (size_t)bid * 2048 + (size_t)t * 8;
        float4 f0 = *(const float4*)(x + base);
        float4 f1 = *(const float4*)(x + base + 4);
        bf16x8 o;
        o[0] = f2bf(f0.x); o[1] = f2bf(f0.y); o[2] = f2bf(f0.z); o[3] = f2bf(f0.w);
        o[4] = f2bf(f1.x); o[5] = f2bf(f1.y); o[6] = f2bf(f1.z); o[7] = f2bf(f1.w);
        *(bf16x8*)(x_bf + base) = o;
    } else if (bid < 192) {              // W_in 128x512 -> W_inT 512x128
        const int bb = bid - 128;
        tconv(tile, W_in, W_inT, 128, 512, bb & 3, bb >> 2, t);
    } else if (bid < 256) {              // Wd 256x256 -> WdbcT rows 0-255
        const int bb = bid - 192;
        tconv(tile, Wd, WdbcT, 256, 256, bb & 7, bb >> 3, t);
    } else if (bid < 320) {              // Wb -> WdbcT rows 256-511
        const int bb = bid - 256;
        tconv(tile, Wb, WdbcT + (size_t)256 * 256, 256, 256, bb & 7, bb >> 3, t);
    } else if (bid < 384) {              // Wc -> WdbcT rows 512-767
        const int bb = bid - 320;
        tconv(tile, Wc, WdbcT + (size_t)512 * 256, 256, 256, bb & 7, bb >> 3, t);
    } else {                             // W_out 256x128 -> W_outT 128x256
        const int bb = bid - 384;
        tconv(tile, W_out, W_outT, 256, 128, bb & 7, bb >> 3, t);
    }
}

// ---------------------------------------------------------------------------
// MFMA GEMM core: 64x64 tile, 256 thr (4 waves), wave = 16-row strip,
// BK=64, LDS rows padded to 72 shorts (conflict-free b128 fragment reads).
// A: M x K row-major bf16; B: N x K row-major bf16 (i.e. B^T, N-major).
// ---------------------------------------------------------------------------
#define BKK 64
#define LP  72

__device__ __forceinline__ void mfma_core64(
    const short* __restrict__ Abf, int lda,
    const short* __restrict__ BbfT, int ldb,
    int K, int r0, int n0,
    short (*As)[LP], short (*Bs)[LP], f32x4 acc[4])
{
    const int tid  = threadIdx.x;
    const int w    = tid >> 6, lane = tid & 63;
    const int srow = tid >> 2, sseg = tid & 3;
    const int frow = lane & 15, fk = (lane >> 4) << 3;

    for (int k0 = 0; k0 < K; k0 += BKK) {
        const short* ag = Abf  + (size_t)(r0 + srow) * lda + k0 + sseg * 16;
        const short* bg = BbfT + (size_t)(n0 + srow) * ldb + k0 + sseg * 16;
        bf16x8 a0 = *(const bf16x8*)ag;
        bf16x8 a1 = *(const bf16x8*)(ag + 8);
        bf16x8 b0 = *(const bf16x8*)bg;
        bf16x8 b1 = *(const bf16x8*)(bg + 8);
        __syncthreads();
        *(bf16x8*)&As[srow][sseg * 16]     = a0;
        *(bf16x8*)&As[srow][sseg * 16 + 8] = a1;
        *(bf16x8*)&Bs[srow][sseg * 16]     = b0;
        *(bf16x8*)&Bs[srow][sseg * 16 + 8] = b1;
        __syncthreads();
#pragma unroll
        for (int kk = 0; kk < BKK; kk += 32) {
            bf16x8 af = *(const bf16x8*)&As[w * 16 + frow][kk + fk];
#pragma unroll
            for (int ct = 0; ct < 4; ++ct) {
                bf16x8 bfr = *(const bf16x8*)&Bs[ct * 16 + frow][kk + fk];
                acc[ct] = __builtin_amdgcn_mfma_f32_16x16x32_bf16(af, bfr, acc[ct], 0, 0, 0);
            }
        }
    }
}

// --------------------------- kernel 1: in_proj (MFMA) -----------------------
// x_bf (2048x128) @ W_in -> xs fp32 + xs bf16 (cols 0-255), sz=silu (256-511)
__global__ __launch_bounds__(256) void k_proj_mfma(
    const short* __restrict__ x_bf, const short* __restrict__ W_inT,
    float* __restrict__ xs, short* __restrict__ xs_bf, float* __restrict__ sz)
{
    __shared__ short As[64][LP], Bs[64][LP];
    f32x4 acc[4] = {};
    const int r0 = blockIdx.y * 64, n0 = blockIdx.x * 64;
    mfma_core64(x_bf, DM, W_inT, DM, DM, r0, n0, As, Bs, acc);
    const int lane = threadIdx.x & 63, w = threadIdx.x >> 6;
    const int rr = r0 + w * 16 + (lane >> 4) * 4;
    const int c0 = n0 + (lane & 15);
#pragma unroll
    for (int ct = 0; ct < 4; ++ct) {
        const int c = c0 + ct * 16;
#pragma unroll
        for (int rg = 0; rg < 4; ++rg) {
            const float v = acc[ct][rg];
            const int r = rr + rg;
            if (c < DI) {
                xs[(size_t)r * DI + c]    = v;
                xs_bf[(size_t)r * DI + c] = f2bf(v);
            } else {
                sz[(size_t)r * DI + (c - DI)] = v / (1.f + __expf(-v));
            }
        }
    }
}

// ------------------- kernel 2: delta / u=Bv*xs / Cv (MFMA) ------------------
__global__ __launch_bounds__(256) void k_dbc_mfma(
    const short* __restrict__ xs_bf, const short* __restrict__ WdbcT,
    const float* __restrict__ xs,
    float* __restrict__ dlt, float* __restrict__ u, float* __restrict__ cvv)
{
    __shared__ short As[64][LP], Bs[64][LP];
    f32x4 acc[4] = {};
    const int r0 = blockIdx.y * 64, n0 = blockIdx.x * 64;
    mfma_core64(xs_bf, DI, WdbcT, DI, DI, r0, n0, As, Bs, acc);
    const int lane = threadIdx.x & 63, w = threadIdx.x >> 6;
    const int rr = r0 + w * 16 + (lane >> 4) * 4;
    const int wsel = n0 >> 8;          // 0: delta, 1: B, 2: C
    const int nb = n0 & 255;
#pragma unroll
    for (int ct = 0; ct < 4; ++ct) {
        const int c = nb + ct * 16 + (lane & 15);
#pragma unroll
        for (int rg = 0; rg < 4; ++rg) {
            const float v = acc[ct][rg];
            const size_t idx = (size_t)(rr + rg) * DI + c;
            if (wsel == 0)      dlt[idx] = v;
            else if (wsel == 1) u[idx]   = v * xs[idx];   // Bv * xs
            else                cvv[idx] = v;
        }
    }
}

// ------------------------ chunked scan (unchanged from R5) ------------------
__global__ __launch_bounds__(256) void k_scan1(
    const float* __restrict__ dlt, const float* __restrict__ u,
    const float* __restrict__ A,
    float* __restrict__ tc, float* __restrict__ dsum)
{
    const int lane = threadIdx.x & 63;
    const int w    = threadIdx.x >> 6;
    const int blk  = blockIdx.x;
    const int b  = blk & 3;
    const int c  = (blk >> 2) & 7;
    const int d0 = ((blk >> 5) * 4 + w) * 4;

    __shared__ float dls[4][4][LC];

    const size_t base = (size_t)b * LLEN * DI + (size_t)c * LC * DI;

    float4 dv = *(const float4*)(dlt + base + (size_t)lane * DI + d0);
    dls[w][0][lane] = dv.x;
    dls[w][1][lane] = dv.y;
    dls[w][2][lane] = dv.z;
    dls[w][3][lane] = dv.w;
    float dsv[4] = { dv.x, dv.y, dv.z, dv.w };
#pragma unroll
    for (int dd = 0; dd < 4; ++dd) {
#pragma unroll
        for (int off = 32; off > 0; off >>= 1)
            dsv[dd] += __shfl_xor(dsv[dd], off);
    }
    __syncthreads();

    float4 c1[4], c2[4], c3[4];
#pragma unroll
    for (int dd = 0; dd < 4; ++dd) {
        float4 a = *(const float4*)(A + (size_t)(d0 + dd) * DS + lane * 4);
        c1[dd] = a;
        c2[dd] = make_float4(0.5f * a.x * a.x, 0.5f * a.y * a.y,
                             0.5f * a.z * a.z, 0.5f * a.w * a.w);
        c3[dd] = make_float4(c2[dd].x * a.x * (1.f / 3.f), c2[dd].y * a.y * (1.f / 3.f),
                             c2[dd].z * a.z * (1.f / 3.f), c2[dd].w * a.w * (1.f / 3.f));
    }

    const float4* up = (const float4*)(u + base) + lane;
    float4 s[4] = {};
    float4 ub[2][4];

#define S1_PRE(NXT, G1)                                                       \
    {                                                                         \
        _Pragma("unroll")                                                     \
        for (int i = 0; i < 4; ++i)                                           \
            ub[NXT][i] = up[(size_t)((G1) * 4 + i) * 64];                     \
    }

#define S1_STEP4(CUR, G)                                                      \
    {                                                                         \
        _Pragma("unroll")                                                     \
        for (int i0 = 0; i0 < 4; ++i0) {                                      \
            const int l = (G) * 4 + i0;                                       \
            const float4 uv = ub[CUR][i0];                                    \
            _Pragma("unroll")                                                 \
            for (int dd = 0; dd < 4; ++dd) {                                  \
                const float dl = dls[w][dd][l];                               \
                s[dd].x = fmaf(TEXP(c1[dd].x, c2[dd].x, c3[dd].x, dl), s[dd].x, dl * uv.x); \
                s[dd].y = fmaf(TEXP(c1[dd].y, c2[dd].y, c3[dd].y, dl), s[dd].y, dl * uv.y); \
                s[dd].z = fmaf(TEXP(c1[dd].z, c2[dd].z, c3[dd].z, dl), s[dd].z, dl * uv.z); \
                s[dd].w = fmaf(TEXP(c1[dd].w, c2[dd].w, c3[dd].w, dl), s[dd].w, dl * uv.w); \
            }                                                                 \
        }                                                                     \
    }

    S1_PRE(0, 0)
    for (int g2 = 0; g2 < 8; ++g2) {
        S1_PRE(1, g2 * 2 + 1)
        S1_STEP4(0, g2 * 2)
        if (g2 < 7) S1_PRE(0, g2 * 2 + 2)
        S1_STEP4(1, g2 * 2 + 1)
    }
#undef S1_PRE
#undef S1_STEP4

    const size_t rbb = ((size_t)(b * 256 + d0)) * NC + c;
#pragma unroll
    for (int dd = 0; dd < 4; ++dd) {
        *(float4*)(tc + (rbb + (size_t)dd * NC) * 256 + lane * 4) = s[dd];
        if (lane == 0) dsum[rbb + dd * NC] = dsv[dd];
    }
}

__global__ __launch_bounds__(256) void k_scan2(
    const float* __restrict__ A, float* __restrict__ tc,
    const float* __restrict__ dsum)
{
    const int lane = threadIdx.x & 63;
    const int w    = threadIdx.x >> 6;
    const int blk  = blockIdx.x;
    const int b = blk & 3;
    const int d = (blk >> 2) * 4 + w;

    float4 a4 = *(const float4*)(A + (size_t)d * DS + lane * 4);
    a4.x *= LOG2E; a4.y *= LOG2E; a4.z *= LOG2E; a4.w *= LOG2E;

    const size_t rb = ((size_t)(b * 256 + d)) * NC;
    float4 s = make_float4(0.f, 0.f, 0.f, 0.f);
#pragma unroll
    for (int c = 0; c < NC; ++c) {
        float* p = tc + (rb + c) * 256 + lane * 4;
        float4 T = *(const float4*)p;
        float  Dc = dsum[rb + c];
        *(float4*)p = s;                      // s_init[c]
        s.x = exp2f(a4.x * Dc) * s.x + T.x;
        s.y = exp2f(a4.y * Dc) * s.y + T.y;
        s.z = exp2f(a4.z * Dc) * s.z + T.z;
        s.w = exp2f(a4.w * Dc) * s.w + T.w;
    }
}

__global__ __launch_bounds__(256) void k_scan3(
    const float* __restrict__ dlt, const float* __restrict__ u,
    const float* __restrict__ cv, const float* __restrict__ A,
    const float* __restrict__ tc, float* __restrict__ y)
{
    const int lane = threadIdx.x & 63;
    const int w    = threadIdx.x >> 6;
    const int blk  = blockIdx.x;
    const int b  = blk & 3;
    const int c  = (blk >> 2) & 7;
    const int d0 = ((blk >> 5) * 4 + w) * 4;

    __shared__ float dls[4][4][LC];
    __shared__ float T[4][LC][33];

    const size_t base = (size_t)b * LLEN * DI + (size_t)c * LC * DI;

    float4 dv = *(const float4*)(dlt + base + (size_t)lane * DI + d0);
    dls[w][0][lane] = dv.x;
    dls[w][1][lane] = dv.y;
    dls[w][2][lane] = dv.z;
    dls[w][3][lane] = dv.w;
    __syncthreads();

    float4 c1[4], c2[4], c3[4];
#pragma unroll
    for (int dd = 0; dd < 4; ++dd) {
        float4 a = *(const float4*)(A + (size_t)(d0 + dd) * DS + lane * 4);
        c1[dd] = a;
        c2[dd] = make_float4(0.5f * a.x * a.x, 0.5f * a.y * a.y,
                             0.5f * a.z * a.z, 0.5f * a.w * a.w);
        c3[dd] = make_float4(c2[dd].x * a.x * (1.f / 3.f), c2[dd].y * a.y * (1.f / 3.f),
                             c2[dd].z * a.z * (1.f / 3.f), c2[dd].w * a.w * (1.f / 3.f));
    }

    const float4* up = (const float4*)(u + base) + lane;
    const float4* cp = (const float4*)(cv + base) + lane;
    float* yb = y + base;

    const size_t rbb = ((size_t)(b * 256 + d0)) * NC + c;
    float4 s[4];
#pragma unroll
    for (int dd = 0; dd < 4; ++dd)
        s[dd] = *(const float4*)(tc + (rbb + (size_t)dd * NC) * 256 + lane * 4);

    float4 ub[2][4], cb[2][4];
    float  p[4][8];

#define S3_PRE(NXT, G1)                                                       \
    {                                                                         \
        _Pragma("unroll")                                                     \
        for (int i = 0; i < 4; ++i) {                                         \
            ub[NXT][i] = up[(size_t)((G1) * 4 + i) * 64];                     \
            cb[NXT][i] = cp[(size_t)((G1) * 4 + i) * 64];                     \
        }                                                                     \
    }

#define S3_STEP4(CUR, G, PBASE)                                               \
    {                                                                         \
        _Pragma("unroll")                                                     \
        for (int i0 = 0; i0 < 4; ++i0) {                                      \
            const int l = (G) * 4 + i0;                                       \
            const float4 uv = ub[CUR][i0];                                    \
            const float4 cV = cb[CUR][i0];                                    \
            _Pragma("unroll")                                                 \
            for (int dd = 0; dd < 4; ++dd) {                                  \
                const float dl = dls[w][dd][l];                               \
                s[dd].x = fmaf(TEXP(c1[dd].x, c2[dd].x, c3[dd].x, dl), s[dd].x, dl * uv.x); \
                s[dd].y = fmaf(TEXP(c1[dd].y, c2[dd].y, c3[dd].y, dl), s[dd].y, dl * uv.y); \
                s[dd].z = fmaf(TEXP(c1[dd].z, c2[dd].z, c3[dd].z, dl), s[dd].z, dl * uv.z); \
                s[dd].w = fmaf(TEXP(c1[dd].w, c2[dd].w, c3[dd].w, dl), s[dd].w, dl * uv.w); \
                p[dd][(PBASE) + i0] =                                         \
                    fmaf(s[dd].w, cV.w, fmaf(s[dd].z, cV.z,                   \
                         fmaf(s[dd].y, cV.y, s[dd].x * cV.x)));               \
            }                                                                 \
        }                                                                     \
    }

#define S3_FLUSH(GODD)                                                        \
    {                                                                         \
        float* tr = &T[w][lane][0];                                           \
        _Pragma("unroll")                                                     \
        for (int dd = 0; dd < 4; ++dd) {                                      \
            *(float4*)(tr + dd * 8)     = make_float4(p[dd][0], p[dd][1], p[dd][2], p[dd][3]); \
            *(float4*)(tr + dd * 8 + 4) = make_float4(p[dd][4], p[dd][5], p[dd][6], p[dd][7]); \
        }                                                                     \
        const int cc = lane & 31, seg = lane >> 5;                            \
        float sm = 0.f;                                                       \
        _Pragma("unroll")                                                     \
        for (int r = 0; r < 32; ++r)                                          \
            sm += T[w][seg * 32 + r][cc];                                     \
        sm += __shfl_xor(sm, 32);                                             \
        if (lane < 32)                                                        \
            yb[(size_t)(((GODD) - 1) * 4 + (cc & 7)) * DI + d0 + (cc >> 3)] = sm; \
    }

    S3_PRE(0, 0)
    for (int g2 = 0; g2 < 8; ++g2) {
        S3_PRE(1, g2 * 2 + 1)
        S3_STEP4(0, g2 * 2, 0)
        if (g2 < 7) S3_PRE(0, g2 * 2 + 2)
        S3_STEP4(1, g2 * 2 + 1, 4)
        S3_FLUSH(g2 * 2 + 1)
        if ((g2 & 1) == 1) __syncthreads();
    }
#undef S3_PRE
#undef S3_STEP4
#undef S3_FLUSH
}

// --------------------------- kernel 4: out GEMM (MFMA) ----------------------
// A = (y * silu(z)) converted to bf16 on the fly; B = W_outT (128x256 N-major)
__global__ __launch_bounds__(256) void k_out_mfma(
    const float* __restrict__ y, const float* __restrict__ szp,
    const short* __restrict__ W_outT, float* __restrict__ out)
{
    __shared__ short As[64][LP], Bs[64][LP];
    f32x4 acc[4] = {};
    const int tid  = threadIdx.x;
    const int w    = tid >> 6, lane = tid & 63;
    const int srow = tid >> 2, sseg = tid & 3;
    const int frow = lane & 15, fk = (lane >> 4) << 3;
    const int r0 = blockIdx.y * 64, n0 = blockIdx.x * 64;

    for (int k0 = 0; k0 < DI; k0 += BKK) {
        const size_t aoff = (size_t)(r0 + srow) * DI + k0 + sseg * 16;
        float4 y0 = *(const float4*)(y + aoff);
        float4 y1 = *(const float4*)(y + aoff + 4);
        float4 y2 = *(const float4*)(y + aoff + 8);
        float4 y3 = *(const float4*)(y + aoff + 12);
        float4 s0 = *(const float4*)(szp + aoff);
        float4 s1 = *(const float4*)(szp + aoff + 4);
        float4 s2 = *(const float4*)(szp + aoff + 8);
        float4 s3 = *(const float4*)(szp + aoff + 12);
        const short* bg = W_outT + (size_t)(n0 + srow) * DI + k0 + sseg * 16;
        bf16x8 b0 = *(const bf16x8*)bg;
        bf16x8 b1 = *(const bf16x8*)(bg + 8);
        bf16x8 a0, a1;
        a0[0] = f2bf(y0.x * s0.x); a0[1] = f2bf(y0.y * s0.y);
        a0[2] = f2bf(y0.z * s0.z); a0[3] = f2bf(y0.w * s0.w);
        a0[4] = f2bf(y1.x * s1.x); a0[5] = f2bf(y1.y * s1.y);
        a0[6] = f2bf(y1.z * s1.z); a0[7] = f2bf(y1.w * s1.w);
        a1[0] = f2bf(y2.x * s2.x); a1[1] = f2bf(y2.y * s2.y);
        a1[2] = f2bf(y2.z * s2.z); a1[3] = f2bf(y2.w * s2.w);
        a1[4] = f2bf(y3.x * s3.x); a1[5] = f2bf(y3.y * s3.y);
        a1[6] = f2bf(y3.z * s3.z); a1[7] = f2bf(y3.w * s3.w);
        __syncthreads();
        *(bf16x8*)&As[srow][sseg * 16]     = a0;
        *(bf16x8*)&As[srow][sseg * 16 + 8] = a1;
        *(bf16x8*)&Bs[srow][sseg * 16]     = b0;
        *(bf16x8*)&Bs[srow][sseg * 16 + 8] = b1;
        __syncthreads();
#pragma unroll
        for (int kk = 0; kk < BKK; kk += 32) {
            bf16x8 af = *(const bf16x8*)&As[w * 16 + frow][kk + fk];
#pragma unroll
            for (int ct = 0; ct < 4; ++ct) {
                bf16x8 bfr = *(const bf16x8*)&Bs[ct * 16 + frow][kk + fk];
                acc[ct] = __builtin_amdgcn_mfma_f32_16x16x32_bf16(af, bfr, acc[ct], 0, 0, 0);
            }
        }
    }

    const int rr = r0 + w * 16 + (lane >> 4) * 4;
    const int c0 = n0 + (lane & 15);
#pragma unroll
    for (int ct = 0; ct < 4; ++ct) {
        const int c = c0 + ct * 16;
#pragma unroll
        for (int rg = 0; rg < 4; ++rg)
            out[(size_t)(rr + rg) * DM + c] = acc[ct][rg];
    }
}

// ---------------------------------------------------------------------------
extern "C" void kernel_launch(void* const* d_in, const int* in_sizes, int n_in,
                              void* d_out, int out_size, void* d_ws, size_t ws_size,
                              hipStream_t stream)
{
    const float* x       = (const float*)d_in[0];
    const float* W_in    = (const float*)d_in[1];
    const float* W_delta = (const float*)d_in[2];
    const float* W_B     = (const float*)d_in[3];
    const float* W_C     = (const float*)d_in[4];
    const float* W_out   = (const float*)d_in[5];
    const float* A       = (const float*)d_in[6];
    // d_in[7] = D, unused by the reference scan

    float* out = (float*)d_out;
    float* ws  = (float*)d_ws;

    const size_t S = (size_t)MROWS * DI;   // 524288 floats per plane (2 MB)
    float* xs  = ws;
    float* sz  = ws + S;
    float* dlt = ws + 2 * S;
    float* u   = ws + 3 * S;
    float* cv  = ws + 4 * S;
    float* yv  = ws + 5 * S;
    float* tc  = ws + 6 * S;                             // 8 MB
    float* dsm = ws + 6 * S + (size_t)1024 * NC * 256;   // 32 KB

    short* bfb    = (short*)(dsm + 1024 * NC);
    short* x_bf   = bfb;                                  // 2048*128
    short* xs_bf  = x_bf + (size_t)MROWS * DM;            // 2048*256
    short* W_inT  = xs_bf + (size_t)MROWS * DI;           // 512*128
    short* WdbcT  = W_inT + (size_t)512 * DM;             // 768*256
    short* W_outT = WdbcT + (size_t)768 * DI;             // 128*256

    k_prep     <<<dim3(416), 256, 0, stream>>>(x, W_in, W_delta, W_B, W_C, W_out,
                                               x_bf, W_inT, WdbcT, W_outT);
    k_proj_mfma<<<dim3(8, 32), 256, 0, stream>>>(x_bf, W_inT, xs, xs_bf, sz);
    k_dbc_mfma <<<dim3(12, 32), 256, 0, stream>>>(xs_bf, WdbcT, xs, dlt, u, cv);
    k_scan1    <<<dim3(512), 256, 0, stream>>>(dlt, u, A, tc, dsm);
    k_scan2    <<<dim3(256), 256, 0, stream>>>(A, tc, dsm);
    k_scan3    <<<dim3(512), 256, 0, stream>>>(dlt, u, cv, A, tc, yv);
    k_out_mfma <<<dim3(2, 32), 256, 0, stream>>>(yv, sz, W_outT, out);
}